// Round 10
// baseline (298.062 us; speedup 1.0000x reference)
//
#include <hip/hip_runtime.h>
#include <math.h>

#define NB 4
#define NF 64
#define NPIX 16384
#define DK 256
#define DV 512
#define QKSCALE 0.4204482f

typedef __attribute__((ext_vector_type(8))) short bf16x8;
typedef __attribute__((ext_vector_type(4))) float f32x4;
#define MFMA16(a, b, c) __builtin_amdgcn_mfma_f32_16x16x32_bf16(a, b, c, 0, 0, 0)

// hardware bf16 convert (v_cvt_pk_bf16_f32, RNE) -- bit-identical to software RNE.
__device__ __forceinline__ short f2bf(float f) {
  __bf16 h = (__bf16)f;
  return __builtin_bit_cast(short, h);
}
__device__ __forceinline__ float bf2f(short s) {
  unsigned u = ((unsigned)(unsigned short)s) << 16;
  return __builtin_bit_cast(float, u);
}

// workspace offsets (float units)
#define OFF_XUPT   0L          // bf16 [4][128y][128x][128c]  4,194,304 f
#define OFF_XAT    4194304L    // bf16 [4][128y][128x][64c]   2,097,152 f
#define OFF_NBT    6291456L    // bf16 frag-packed [8bi][1024nt][4ct][64lane][4]  4,194,304 f
#define OFF_NZT    10485760L   // bf16 frag-packed [8bi][1024nt][2ks][64lane][8]  4,194,304 f
#define OFF_GPART  14680064L   // bf16 [8bi][128ch][256][80] 10,485,760 f
#define OFF_WB1    25165824L   // bf16 frag-packed [9sh][4ct][4ks][512]  36,864 f
#define OFF_WB2    25202688L   // bf16 frag-packed [9sh][4ct][2ks][512]  18,432 f
#define OFF_STYLE  25221120L   // [4][64] fp32                      256
#define OFF_RGBS   25221376L   // [4][3][128][128] fp32         196,608
#define OFF_QWB    25417984L   // bf16 frag-packed [2][16hd][2ks][512]   16,384 f
#define OFF_KWB    25434368L   // bf16 frag-packed [2][4q][4dt][2ks][512] 16,384 f
#define OFF_F1WB   25450752L   // bf16 frag-packed [2][8jt][2ks][512]     8,192 f
#define OFF_F2WB   25458944L   // bf16 frag-packed [2][4ct][2p][2ks][512] 8,192 f
#define OFF_MTT    25467136L   // bf16 frag-packed [8bi][4ct][8h][512]   65,536 f
#define OFF_GSUM   25532672L   // fp32 [8bi][256][80]           163,840 f
// total 25,696,512 floats = 102.8 MB

#define CDIV(a,b) (((a)+(b)-1)/(b))

// ---------------- fp32 -> bf16 FRAGMENT-PACKED attn weights + style (block 384) ----------
__global__ void cvt4_kernel(const float* __restrict__ qw, const float* __restrict__ kw,
                            const float* __restrict__ f1w, const float* __restrict__ f2w,
                            short* __restrict__ qwP, short* __restrict__ kwP,
                            short* __restrict__ f1P, short* __restrict__ f2P,
                            const float* __restrict__ istyle, const float* __restrict__ sw,
                            const float* __restrict__ sb, float* __restrict__ styleb) {
  if (blockIdx.x == 384) {   // folded style kernel
    int b = threadIdx.x >> 6;
    int c = threadIdx.x & 63;
    float a = 0.f;
    const float* ip = istyle + b * 512;
    const float* wp = sw + c * 512;
    for (int l = 0; l < 512; ++l) a += ip[l] * wp[l];
    styleb[b * 64 + c] = a + sb[c];
    return;
  }
  int i = blockIdx.x * 256 + threadIdx.x;   // 98304 total
  if (i < 32768) {
    int i_t = i >> 14, rem = i & 16383;
    int hd = rem >> 10, ks = (rem >> 9) & 1, lane = (rem >> 3) & 63, j = rem & 7;
    int l15 = lane & 15, quad = lane >> 4;
    qwP[i] = f2bf(qw[i_t * 16384 + (hd * 16 + l15) * 64 + ks * 32 + quad * 8 + j]);
  } else if (i < 65536) {
    int ii = i - 32768;
    int i_t = ii >> 14, rem = ii & 16383;
    int q = rem >> 12, dt = (rem >> 10) & 3, ks = (rem >> 9) & 1, lane = (rem >> 3) & 63, j = rem & 7;
    int l15 = lane & 15, quad = lane >> 4;
    kwP[ii] = f2bf(kw[i_t * 16384 + (q * 64 + dt * 16 + l15) * 64 + ks * 32 + quad * 8 + j]);
  } else if (i < 81920) {
    int ii = i - 65536;
    int i_t = ii >> 13, rem = ii & 8191;
    int jt = rem >> 10, ks = (rem >> 9) & 1, lane = (rem >> 3) & 63, j = rem & 7;
    int l15 = lane & 15, quad = lane >> 4;
    f1P[ii] = f2bf(f1w[i_t * 8192 + (jt * 16 + l15) * 64 + ks * 32 + quad * 8 + j]);
  } else {
    int ii = i - 81920;
    int i_t = ii >> 13, rem = ii & 8191;
    int ct = rem >> 11, p = (rem >> 10) & 1, ks = (rem >> 9) & 1, lane = (rem >> 3) & 63, j = rem & 7;
    int l15 = lane & 15, quad = lane >> 4;
    f2P[ii] = f2bf(f2w[i_t * 8192 + (ct * 16 + l15) * 128 + p * 64 + ks * 32 + quad * 8 + j]);
  }
}

// ---------------- fused bilinear up2 + NCHW->NHWC bf16 (x path), coalesced stores --------
__global__ __launch_bounds__(256) void up2t_kernel(const float* __restrict__ in,
                                                   short* __restrict__ outT) {
  __shared__ float row[64 * 132];   // [xin][c] y-interpolated row
  int b = blockIdx.y, y = blockIdx.x, tid = threadIdx.x;
  int w = tid >> 6, lane = tid & 63, quad = lane >> 4, l15 = lane & 15;
  float iy = y * 0.5f - 0.25f;
  int y0 = (int)floorf(iy); float wy = iy - (float)y0;
  int ylo = y0 < 0 ? 0 : y0;
  int yhi = y0 + 1 > 63 ? 63 : y0 + 1;
  for (int it = 0; it < 32; ++it) {
    int idx = it * 256 + tid;
    int c = idx >> 6, xin = idx & 63;
    const float* bp = in + ((long)(b * 128 + c)) * 4096;
    float v0 = bp[ylo * 64 + xin];
    float v1 = bp[yhi * 64 + xin];
    row[xin * 132 + c] = (1.f - wy) * v0 + wy * v1;
  }
  __syncthreads();
  long ybase = (((long)(b * 128 + y)) * 128) * 128;
#pragma unroll
  for (int s = 0; s < 8; ++s) {
    int x = w * 32 + s * 4 + quad;
    float ix = x * 0.5f - 0.25f;
    int x0 = (int)floorf(ix); float wx = ix - (float)x0;
    int xlo = x0 < 0 ? 0 : x0;
    int xhi = x0 + 1 > 63 ? 63 : x0 + 1;
    bf16x8 pack;
#pragma unroll
    for (int j = 0; j < 8; ++j) {
      int c = l15 * 8 + j;
      float v = (1.f - wx) * row[xlo * 132 + c] + wx * row[xhi * 132 + c];
      pack[j] = f2bf(v);
    }
    *(bf16x8*)(outT + ybase + (long)x * 128 + l15 * 8) = pack;
  }
}

// ---------------- noise NCHW fp32 -> B-fragment-packed bf16, float4 staging --------------
// grid (64, NB, 2): block covers 256 px x 64 c. Staging 1KB/wave-instr (float4).
__global__ __launch_bounds__(256) void nzt_kernel(const float* __restrict__ nz1,
                                                  const float* __restrict__ nz2,
                                                  short* __restrict__ nzP) {
  __shared__ short tile[64 * 264];   // [c][px256 pad264]
  int i = blockIdx.z, b = blockIdx.y;
  long n0 = (long)blockIdx.x * 256;
  const float* nz = (i == 0) ? nz1 : nz2;
  int tid = threadIdx.x;
  const float* src = nz + (long)b * 64 * NPIX + n0;
#pragma unroll
  for (int k = 0; k < 16; ++k) {
    int idx = tid + k * 256;
    int c = idx >> 6, g = idx & 63;
    float4 v = *(const float4*)(src + (long)c * NPIX + g * 4);
    short* tp = tile + c * 264 + g * 4;
    tp[0] = f2bf(v.x); tp[1] = f2bf(v.y); tp[2] = f2bf(v.z); tp[3] = f2bf(v.w);
  }
  __syncthreads();
  long fragb = ((long)(i * NB + b)) * 1024 + blockIdx.x * 16;
#pragma unroll
  for (int v = 0; v < 8; ++v) {
    int slot = tid + v * 256;
    int frag = slot >> 6, lane = slot & 63;
    int nt = frag >> 1, ks = frag & 1;
    int l15 = lane & 15, quad = lane >> 4;
    bf16x8 pack;
#pragma unroll
    for (int j = 0; j < 8; ++j)
      pack[j] = tile[(ks * 32 + quad * 8 + j) * 264 + nt * 16 + l15];
    *(bf16x8*)(nzP + ((fragb + nt) * 2 + ks) * 512 + lane * 8) = pack;
  }
}

// ---------------- demod weight prep (both convs in one launch) ---------------------------
__global__ void wnorm2_kernel(const float* __restrict__ W1, const float* __restrict__ W2,
                              short* __restrict__ wb1, short* __restrict__ wb2) {
  int which = blockIdx.x >> 6;
  int co = blockIdx.x & 63;
  const float* W = which ? W2 : W1;
  short* wbP = which ? wb2 : wb1;
  int CI = which ? 64 : 128;
  int n = CI * 9;
  int KS = CI >> 5;
  __shared__ float red[256];
  float s = 0.f;
  for (int idx = threadIdx.x; idx < n; idx += 256) {
    float w2 = 2.0f * W[co * n + idx];
    s += w2 * w2;
  }
  red[threadIdx.x] = s;
  __syncthreads();
  for (int off = 128; off > 0; off >>= 1) {
    if (threadIdx.x < off) red[threadIdx.x] += red[threadIdx.x + off];
    __syncthreads();
  }
  float sc = rsqrtf(red[0] + 1e-8f);
  int ct = co >> 4, l15 = co & 15;
  for (int idx = threadIdx.x; idx < n; idx += 256) {
    int ci = idx / 9, k = idx - ci * 9;
    int ks = ci >> 5, quad = (ci >> 3) & 3, j = ci & 7;
    wbP[((k * 4 + ct) * KS + ks) * 512 + (quad * 16 + l15) * 8 + j] =
        f2bf(2.0f * W[co * n + idx] * sc);
  }
}

// ---------------- pk: Gpart(bf16)[bi][ch][256][80] = exp(kw@X) @ [X^T | 1 | 0] -----------
__global__ __launch_bounds__(256, 4) void pk_kernel(const float* __restrict__ nz1,
                                                    const float* __restrict__ nz2,
                                                    const short* __restrict__ nzP,
                                                    const short* __restrict__ kwP,
                                                    short* __restrict__ Gpartb) {
  __shared__ __attribute__((aligned(16))) char lds[39168];
  int bi = blockIdx.x, ch = blockIdx.y;
  int i = bi >> 2, b = bi & 3;
  const float* nz = (i == 0) ? nz1 : nz2;
  const short* kwP_i = kwP + i * (DK * NF);
  int tid = threadIdx.x;
  int w = tid >> 6, lane = tid & 63, quad = lane >> 4, l15 = lane & 15;
  int n0 = ch * 128;
  short* Xb = (short*)lds;               // [80][136]
  short* Ph = (short*)(lds + 21760);     // [64][136]
  // float4 staging: wave = 2 c-rows x 512B contiguous
#pragma unroll
  for (int k = 0; k < 8; ++k) {
    int idx = tid + k * 256;
    int c = idx >> 5, g = idx & 31;
    float4 v = *(const float4*)(nz + ((long)b * 64 + c) * NPIX + n0 + g * 4);
    short* xp = Xb + c * 136 + g * 4;
    xp[0] = f2bf(v.x); xp[1] = f2bf(v.y); xp[2] = f2bf(v.z); xp[3] = f2bf(v.w);
  }
  for (int k = 0; k < 8; ++k) {
    int idx = tid + k * 256;
    int c = 64 + (idx >> 7), n = idx & 127;
    Xb[c * 136 + n] = (c == 64) ? (short)0x3F80 : (short)0;
  }
  // hoist B fragments for this wave's two n-tiles from nzP (coalesced 1KB loads)
  bf16x8 bfr[2][2];
#pragma unroll
  for (int j = 0; j < 2; ++j)
#pragma unroll
    for (int ks = 0; ks < 2; ++ks)
      bfr[j][ks] = *(const bf16x8*)(nzP +
          (((long)bi * 1024 + ch * 8 + 2 * w + j) * 2 + ks) * 512 + lane * 8);
  __syncthreads();
  for (int q = 0; q < 4; ++q) {
    f32x4 acc[2][4];
#pragma unroll
    for (int j = 0; j < 2; ++j)
#pragma unroll
      for (int dt = 0; dt < 4; ++dt) acc[j][dt] = (f32x4){0.f, 0.f, 0.f, 0.f};
#pragma unroll
    for (int j = 0; j < 2; ++j) {
#pragma unroll
      for (int ks = 0; ks < 2; ++ks) {
#pragma unroll
        for (int dt = 0; dt < 4; ++dt) {
          bf16x8 afr = *(const bf16x8*)(kwP_i + (((q * 4 + dt) * 2 + ks) * 512 + lane * 8));
          acc[j][dt] = MFMA16(afr, bfr[j][ks], acc[j][dt]);
        }
      }
    }
#pragma unroll
    for (int j = 0; j < 2; ++j) {
      int ntile = 2 * w + j;
#pragma unroll
      for (int dt = 0; dt < 4; ++dt)
#pragma unroll
        for (int r = 0; r < 4; ++r) {
          float p = __expf(acc[j][dt][r] * QKSCALE);
          Ph[(dt * 16 + quad * 4 + r) * 136 + ntile * 16 + l15] = f2bf(p);
        }
    }
    __syncthreads();
#pragma unroll
    for (int ct = 0; ct < 5; ++ct) {
      f32x4 g = (f32x4){0.f, 0.f, 0.f, 0.f};
#pragma unroll
      for (int ks = 0; ks < 4; ++ks) {
        bf16x8 afr = *(const bf16x8*)(Ph + (w * 16 + l15) * 136 + ks * 32 + quad * 8);
        bf16x8 bfr2 = *(const bf16x8*)(Xb + (ct * 16 + l15) * 136 + ks * 32 + quad * 8);
        g = MFMA16(afr, bfr2, g);
      }
#pragma unroll
      for (int r = 0; r < 4; ++r) {
        int row = q * 64 + w * 16 + quad * 4 + r;
        Gpartb[(((long)bi * 128 + ch) * 256 + row) * 80 + ct * 16 + l15] = f2bf(g[r]);
      }
    }
    __syncthreads();
  }
}

// ---------------- gsum: reduce Gpart over ch -> Gsum fp32 [bi][256][80], short4/lane -----
// 20480 elems/bi = 5120 groups-of-4; total 8*5120 = 40960 = 160 blocks x 256.
__global__ __launch_bounds__(256) void gsum_kernel(const short* __restrict__ Gpartb,
                                                   float* __restrict__ Gsum) {
  int idx4 = blockIdx.x * 256 + threadIdx.x;   // 40960 total
  int bi = idx4 / 5120;
  int rem4 = idx4 - bi * 5120;
  const short* gp = Gpartb + (long)bi * 128 * 20480 + rem4 * 4;
  float a0 = 0.f, a1 = 0.f, a2 = 0.f, a3 = 0.f;
#pragma unroll 8
  for (int ch = 0; ch < 128; ++ch) {
    short4 v = *(const short4*)(gp + (long)ch * 20480);
    a0 += bf2f(v.x); a1 += bf2f(v.y); a2 += bf2f(v.z); a3 += bf2f(v.w);
  }
  float4 o = {a0, a1, a2, a3};
  *(float4*)(Gsum + (long)bi * 20480 + rem4 * 4) = o;
}

// ---------------- ctxM: Gsum -> ctx -> MtP (fragment-packed) -----------------------------
__global__ __launch_bounds__(256) void ctxM_kernel(const float* __restrict__ Gsum,
                                                   const float* __restrict__ vw,
                                                   const float* __restrict__ ow,
                                                   short* __restrict__ MtP) {
  int i = blockIdx.z, b = blockIdx.y, dt = blockIdx.x * 16;
  int h = dt >> 5;
  __shared__ float Gs[16][81];
  __shared__ float ctxs[16][68];
  int t = threadIdx.x;
  const float* gsb = Gsum + ((long)(i * NB + b)) * 20480;
  for (int idx = t; idx < 1280; idx += 256) {
    int dl = idx / 80, c = idx - dl * 80;
    Gs[dl][c] = gsb[(dt + dl) * 80 + c];
  }
  __syncthreads();
  const float* vw_i = vw + (long)i * DV * NF;
  const float* ow_i = ow + (long)i * NF * DV;
  for (int idx = t; idx < 1024; idx += 256) {
    int dl = idx & 15, e = idx >> 4;
    const float* vp = vw_i + (h * 64 + e) * 64;
    float a = 0.f;
#pragma unroll
    for (int c = 0; c < 64; ++c) a += Gs[dl][c] * vp[c];
    ctxs[dl][e] = a / Gs[dl][64];
  }
  __syncthreads();
  // MtP[bi][ct4][h8][lane][8] = MtT[c=ct*16+l15][d=h*32+quad*8+r]
  short* mtp = MtP + ((long)(i * NB + b)) * 16384;
  for (int idx = t; idx < 1024; idx += 256) {
    int dl = idx & 15, c = idx >> 4;
    const float* op = ow_i + c * 512 + h * 64;
    float a = 0.f;
#pragma unroll
    for (int e = 0; e < 64; ++e) a += op[e] * ctxs[dl][e];
    int d = dt + dl;
    int ct = c >> 4, l15 = c & 15, hh = d >> 5, quad = (d >> 3) & 3, r = d & 7;
    mtp[((ct * 8 + hh) * 64 + quad * 16 + l15) * 8 + r] = f2bf(a);
  }
}

// ---------------- attnd4: fused attn+FF, bi-major grid for weight-set locality -----------
// grid (8 bi, 256 x), block 256 = 4 waves, 16 px/wave. Per-wave LDS 4096 B.
// launch_bounds (256,6): (256,8) raised occupancy 44->63% but doubled HBM traffic
// (FETCH 8.7->19.1 MB, WRITE 16.4->38.7 MB) and was net slower -- keep 6.
__global__ __launch_bounds__(256, 6) void attnd4_kernel(
    const short* __restrict__ nzP, const short* __restrict__ qwP,
    const short* __restrict__ MtP, const float* __restrict__ ob,
    const float* __restrict__ gap, const short* __restrict__ f1P,
    const float* __restrict__ f1b, const short* __restrict__ f2P,
    const float* __restrict__ f2b, const float* __restrict__ gfp,
    short* __restrict__ noutP) {
  __shared__ __attribute__((aligned(16))) short lds[4 * 2048];
  int bi = blockIdx.x;
  int i = bi >> 2;
  int tid = threadIdx.x;
  int w = tid >> 6, lane = tid & 63, quad = lane >> 4, l15 = lane & 15;
  short* Xt = lds + w * 2048;     // [16][72]
  short* Es = Xt + 1152;          // [16][56]
  float ga = gap[i], gf = gfp[i];
  const short* qwP_i = qwP + i * (DK * NF);
  const short* f1P_i = f1P + i * (128 * 64);
  const float* f1b_i = f1b + i * 128;
  const short* f2P_i = f2P + i * (64 * 128);
  const float* f2b_i = f2b + i * 64;
  const float* ob_i = ob + i * 64;
  long ntile = (long)bi * 1024 + blockIdx.y * 4 + w;
  // stage X: two fully-coalesced 1KB fragment loads, mirror into LDS for residual
  const short* nb = nzP + ntile * 1024;
  bf16x8 xfr0 = *(const bf16x8*)(nb + lane * 8);
  bf16x8 xfr1 = *(const bf16x8*)(nb + 512 + lane * 8);
  *(bf16x8*)(Xt + l15 * 72 + quad * 8) = xfr0;
  *(bf16x8*)(Xt + l15 * 72 + 32 + quad * 8) = xfr1;
  const short* mtp = MtP + (long)bi * 16384;
  f32x4 acc2[4];
#pragma unroll
  for (int ct = 0; ct < 4; ++ct) acc2[ct] = (f32x4){0.f, 0.f, 0.f, 0.f};
  // per-head: GEMM1 (q) -> softmax -> E-strip -> GEMM2 chunk
#pragma unroll
  for (int h = 0; h < 8; ++h) {
    f32x4 q[2];
#pragma unroll
    for (int dd = 0; dd < 2; ++dd) {
      int hd = 2 * h + dd;
      q[dd] = (f32x4){0.f, 0.f, 0.f, 0.f};
      bf16x8 a0 = *(const bf16x8*)(qwP_i + (hd * 2 + 0) * 512 + lane * 8);
      q[dd] = MFMA16(a0, xfr0, q[dd]);
      bf16x8 a1 = *(const bf16x8*)(qwP_i + (hd * 2 + 1) * 512 + lane * 8);
      q[dd] = MFMA16(a1, xfr1, q[dd]);
    }
    float part = 0.f;
#pragma unroll
    for (int dd = 0; dd < 2; ++dd)
#pragma unroll
      for (int r = 0; r < 4; ++r) {
        float e = __expf(q[dd][r] * QKSCALE);
        q[dd][r] = e;
        part += e;
      }
    float p2 = part + __shfl_xor(part, 16);
    float s = p2 + __shfl_xor(p2, 32);
    float inv = 1.0f / s;
#pragma unroll
    for (int dd = 0; dd < 2; ++dd) {
      short4 ev;
      ev.x = f2bf(q[dd][0] * inv); ev.y = f2bf(q[dd][1] * inv);
      ev.z = f2bf(q[dd][2] * inv); ev.w = f2bf(q[dd][3] * inv);
      *(short4*)(Es + l15 * 56 + dd * 16 + quad * 4) = ev;
    }
    bf16x8 efr = *(const bf16x8*)(Es + l15 * 56 + quad * 8);
#pragma unroll
    for (int ct = 0; ct < 4; ++ct) {
      bf16x8 afr = *(const bf16x8*)(mtp + (ct * 8 + h) * 512 + lane * 8);
      acc2[ct] = MFMA16(afr, efr, acc2[ct]);
    }
  }
  // residual y = x + ga*(o + ob): x from LDS bf16, y back to Xt + fp32 regs
  float yreg[4][4];
#pragma unroll
  for (int ct = 0; ct < 4; ++ct) {
    int c0 = ct * 16 + quad * 4;
    short4 xs = *(const short4*)(Xt + l15 * 72 + c0);
    float xv[4] = {bf2f(xs.x), bf2f(xs.y), bf2f(xs.z), bf2f(xs.w)};
    short4 ys;
#pragma unroll
    for (int r = 0; r < 4; ++r) yreg[ct][r] = xv[r] + ga * (acc2[ct][r] + ob_i[c0 + r]);
    ys.x = f2bf(yreg[ct][0]); ys.y = f2bf(yreg[ct][1]);
    ys.z = f2bf(yreg[ct][2]); ys.w = f2bf(yreg[ct][3]);
    *(short4*)(Xt + l15 * 72 + c0) = ys;
  }
  bf16x8 yfr0 = *(const bf16x8*)(Xt + l15 * 72 + quad * 8);
  bf16x8 yfr1 = *(const bf16x8*)(Xt + l15 * 72 + 32 + quad * 8);
  // GEMM3: h1[128j x 16n]
  f32x4 acc3[8];
#pragma unroll
  for (int jt = 0; jt < 8; ++jt) {
    acc3[jt] = (f32x4){0.f, 0.f, 0.f, 0.f};
    bf16x8 a0 = *(const bf16x8*)(f1P_i + (jt * 2 + 0) * 512 + lane * 8);
    acc3[jt] = MFMA16(a0, yfr0, acc3[jt]);
    bf16x8 a1 = *(const bf16x8*)(f1P_i + (jt * 2 + 1) * 512 + lane * 8);
    acc3[jt] = MFMA16(a1, yfr1, acc3[jt]);
  }
  // GEMM4 in 2 chunks of 64 j through the Xt strip
  f32x4 acc4[4];
#pragma unroll
  for (int ct = 0; ct < 4; ++ct) acc4[ct] = (f32x4){0.f, 0.f, 0.f, 0.f};
#pragma unroll
  for (int p = 0; p < 2; ++p) {
#pragma unroll
    for (int jj = 0; jj < 4; ++jj) {
      int jt = p * 4 + jj;
      short4 hs;
#pragma unroll
      for (int r = 0; r < 4; ++r) {
        float a = acc3[jt][r] + f1b_i[jt * 16 + quad * 4 + r];
        a = a > 0.f ? a : 0.2f * a;
        ((short*)&hs)[r] = f2bf(a);
      }
      *(short4*)(Xt + l15 * 72 + jj * 16 + quad * 4) = hs;
    }
    bf16x8 h0 = *(const bf16x8*)(Xt + l15 * 72 + quad * 8);
    bf16x8 h1 = *(const bf16x8*)(Xt + l15 * 72 + 32 + quad * 8);
#pragma unroll
    for (int ct = 0; ct < 4; ++ct) {
      bf16x8 a0 = *(const bf16x8*)(f2P_i + ((ct * 2 + p) * 2 + 0) * 512 + lane * 8);
      acc4[ct] = MFMA16(a0, h0, acc4[ct]);
      bf16x8 a1 = *(const bf16x8*)(f2P_i + ((ct * 2 + p) * 2 + 1) * 512 + lane * 8);
      acc4[ct] = MFMA16(a1, h1, acc4[ct]);
    }
  }
  // output fragment-packed: noutP[ntile][ct][lane][4] -- 512B coalesced per store
#pragma unroll
  for (int ct = 0; ct < 4; ++ct) {
    int c0 = ct * 16 + quad * 4;
    short4 ov;
#pragma unroll
    for (int r = 0; r < 4; ++r)
      ((short*)&ov)[r] = f2bf(yreg[ct][r] + gf * (acc4[ct][r] + f2b_i[c0 + r]));
    *(short4*)(noutP + (ntile * 4 + ct) * 256 + lane * 4) = ov;
  }
}

// ---------------- MFMA 3x3 conv: NHWC bf16 in, frag-packed weights+addend, lrelu, +rgb ---
// grid (2 xh, 128 y, NB). wave w -> one 16-px ntile; block covers 64 px (half row).
__global__ __launch_bounds__(256, 4) void convmfma_kernel(
    const short* __restrict__ inT, int CI, const short* __restrict__ wbP,
    const short* __restrict__ addnP, float* __restrict__ out_nchw,
    short* __restrict__ out_nhwc, const float* __restrict__ rgbw,
    const float* __restrict__ styleb, const float* __restrict__ prev,
    float* __restrict__ rgbs) {
  __shared__ __attribute__((aligned(16))) short Bs[3 * 66 * 40];  // [r][xi][ci32 pad40]
  int xh = blockIdx.x, y = blockIdx.y, b = blockIdx.z;
  int tid = threadIdx.x;
  int w = tid >> 6, lane = tid & 63, quad = lane >> 4, l15 = lane & 15;
  int KS = CI >> 5;
  f32x4 acc[4];
#pragma unroll
  for (int ct = 0; ct < 4; ++ct) acc[ct] = (f32x4){0.f, 0.f, 0.f, 0.f};
  for (int ks = 0; ks < KS; ++ks) {
    if (ks) __syncthreads();
    for (int t = tid; t < 792; t += 256) {
      int ci8 = t & 3, xr = t >> 2;
      int xi = xr % 66, r = xr / 66;
      int gy = y + r - 1, gx = xh * 64 + xi - 1;
      bf16x8 v = {0, 0, 0, 0, 0, 0, 0, 0};
      if (gy >= 0 && gy < 128 && gx >= 0 && gx < 128)
        v = *(const bf16x8*)(inT + (((long)(b * 128 + gy)) * 128 + gx) * CI + ks * 32 + ci8 * 8);
      *(bf16x8*)(Bs + (r * 66 + xi) * 40 + ci8 * 8) = v;
    }
    __syncthreads();
#pragma unroll
    for (int sh = 0; sh < 9; ++sh) {
      int dyv = sh / 3, dxv = sh - dyv * 3;
      const short* wbase = wbP + ((sh * 4) * KS + ks) * 512 + lane * 8;
      bf16x8 a0 = *(const bf16x8*)(wbase);
      bf16x8 a1 = *(const bf16x8*)(wbase + KS * 512);
      bf16x8 a2 = *(const bf16x8*)(wbase + 2 * KS * 512);
      bf16x8 a3 = *(const bf16x8*)(wbase + 3 * KS * 512);
      int xi = w * 16 + l15 + dxv;
      bf16x8 bf = *(const bf16x8*)(Bs + (dyv * 66 + xi) * 40 + quad * 8);
      acc[0] = MFMA16(a0, bf, acc[0]);
      acc[1] = MFMA16(a1, bf, acc[1]);
      acc[2] = MFMA16(a2, bf, acc[2]);
      acc[3] = MFMA16(a3, bf, acc[3]);
    }
  }
  // epilogue: lrelu(conv + addn(frag-packed)), stores, optional rgb
  int x = xh * 64 + w * 16 + l15;
  long nidx = ((long)(b * 128 + y)) * 128 + x;
  long ntile = (long)b * 1024 + y * 8 + xh * 4 + w;
  float p0 = 0.f, p1 = 0.f, p2 = 0.f;
#pragma unroll
  for (int ct = 0; ct < 4; ++ct) {
    short4 ad = *(const short4*)(addnP + (ntile * 4 + ct) * 256 + lane * 4);
    float av[4] = {bf2f(ad.x), bf2f(ad.y), bf2f(ad.z), bf2f(ad.w)};
    float v[4];
#pragma unroll
    for (int r = 0; r < 4; ++r) {
      float a = acc[ct][r] + av[r];
      v[r] = a > 0.f ? a : 0.2f * a;
    }
    if (out_nchw) {
#pragma unroll
      for (int r = 0; r < 4; ++r) {
        int co = ct * 16 + quad * 4 + r;
        out_nchw[((long)(b * 64 + co)) * 16384 + y * 128 + x] = v[r];
      }
    }
    if (out_nhwc) {
      short4 pv;
      pv.x = f2bf(v[0]); pv.y = f2bf(v[1]); pv.z = f2bf(v[2]); pv.w = f2bf(v[3]);
      *(short4*)(out_nhwc + nidx * 64 + ct * 16 + quad * 4) = pv;
    }
    if (rgbw) {
#pragma unroll
      for (int r = 0; r < 4; ++r) {
        int co = ct * 16 + quad * 4 + r;
        float mv = (styleb[b * 64 + co] + 1.0f) * v[r];
        p0 += rgbw[co] * mv;
        p1 += rgbw[64 + co] * mv;
        p2 += rgbw[128 + co] * mv;
      }
    }
  }
  if (rgbw) {
    p0 += __shfl_xor(p0, 16); p0 += __shfl_xor(p0, 32);
    p1 += __shfl_xor(p1, 16); p1 += __shfl_xor(p1, 32);
    p2 += __shfl_xor(p2, 16); p2 += __shfl_xor(p2, 32);
    if (quad == 0) {
      long pi = y * 128 + x;
      rgbs[((long)(b * 3 + 0)) * 16384 + pi] = p0 + prev[((long)(b * 3 + 0)) * 16384 + pi];
      rgbs[((long)(b * 3 + 1)) * 16384 + pi] = p1 + prev[((long)(b * 3 + 1)) * 16384 + pi];
      rgbs[((long)(b * 3 + 2)) * 16384 + pi] = p2 + prev[((long)(b * 3 + 2)) * 16384 + pi];
    }
  }
}

// ---------------- fused bilinear up2 + [1,2,1] blur (rgb tail) ---------------------------
__global__ void upblur_kernel(const float* __restrict__ rgbs, float* __restrict__ out) {
  __shared__ float rows[3][128];
  int bc = blockIdx.y, Y = blockIdx.x, X = threadIdx.x;
  int m = Y >> 1;
  const float* base = rgbs + (long)bc * 16384;
  for (int t = X; t < 384; t += 256) {
    int sr = t >> 7, xx = t & 127;
    int rr = m - 1 + sr;
    rr = rr < 0 ? 0 : (rr > 127 ? 127 : rr);
    rows[sr][xx] = base[rr * 128 + xx];
  }
  __syncthreads();
  const float w3[3] = {1.f, 2.f, 1.f};
  float s = 0.f;
#pragma unroll
  for (int dy = -1; dy <= 1; ++dy) {
    int Yv = Y + dy;
    if (Yv < 0 || Yv > 255) continue;
    float iy = Yv * 0.5f - 0.25f;
    int y0 = (int)floorf(iy); float wy = iy - (float)y0;
    int ylo = y0 < 0 ? 0 : y0;
    int yhi = y0 + 1 > 127 ? 127 : y0 + 1;
    int slo = ylo - m + 1, shi = yhi - m + 1;
#pragma unroll
    for (int dx = -1; dx <= 1; ++dx) {
      int Xv = X + dx;
      if (Xv < 0 || Xv > 255) continue;
      float ix = Xv * 0.5f - 0.25f;
      int x0 = (int)floorf(ix); float wx = ix - (float)x0;
      int xlo = x0 < 0 ? 0 : x0;
      int xhi = x0 + 1 > 127 ? 127 : x0 + 1;
      float v = (1.f - wy) * ((1.f - wx) * rows[slo][xlo] + wx * rows[slo][xhi])
              + wy * ((1.f - wx) * rows[shi][xlo] + wx * rows[shi][xhi]);
      s += w3[dy + 1] * w3[dx + 1] * v;
    }
  }
  out[(long)bc * 65536 + Y * 256 + X] = s * (1.0f / 16.0f);
}

extern "C" void kernel_launch(void* const* d_in, const int* in_sizes, int n_in,
                              void* d_out, int out_size, void* d_ws, size_t ws_size,
                              hipStream_t stream) {
  (void)in_sizes; (void)n_in; (void)out_size; (void)ws_size;
  const float* x        = (const float*)d_in[0];
  const float* prev_rgb = (const float*)d_in[1];
  const float* istyle   = (const float*)d_in[2];
  const float* noise1   = (const float*)d_in[3];
  const float* noise2   = (const float*)d_in[4];
  const float* conv1_w  = (const float*)d_in[5];
  const float* conv2_w  = (const float*)d_in[6];
  const float* style_w  = (const float*)d_in[7];
  const float* style_b  = (const float*)d_in[8];
  const float* rgb_w    = (const float*)d_in[9];
  const float* qw       = (const float*)d_in[10];
  const float* kw       = (const float*)d_in[11];
  const float* vw       = (const float*)d_in[12];
  const float* ow       = (const float*)d_in[13];
  const float* ob       = (const float*)d_in[14];
  const float* ga       = (const float*)d_in[15];
  const float* f1w      = (const float*)d_in[16];
  const float* f1b      = (const float*)d_in[17];
  const float* f2w      = (const float*)d_in[18];
  const float* f2b      = (const float*)d_in[19];
  const float* gf       = (const float*)d_in[20];
  float* out_x   = (float*)d_out;
  float* out_rgb = out_x + 4194304;
  float* ws = (float*)d_ws;

  short* xupT   = (short*)(ws + OFF_XUPT);
  short* xaT    = (short*)(ws + OFF_XAT);
  short* nbufP  = (short*)(ws + OFF_NBT);
  short* nzP    = (short*)(ws + OFF_NZT);
  short* Gpartb = (short*)(ws + OFF_GPART);
  short* wb1    = (short*)(ws + OFF_WB1);
  short* wb2    = (short*)(ws + OFF_WB2);
  float* styleb = ws + OFF_STYLE;
  float* rgbs   = ws + OFF_RGBS;
  short* qwP    = (short*)(ws + OFF_QWB);
  short* kwP    = (short*)(ws + OFF_KWB);
  short* f1P    = (short*)(ws + OFF_F1WB);
  short* f2P    = (short*)(ws + OFF_F2WB);
  short* MtP    = (short*)(ws + OFF_MTT);
  float* Gsum   = ws + OFF_GSUM;

  // prep (style folded into cvt4 block 384; both wnorms in one launch)
  cvt4_kernel<<<385, 256, 0, stream>>>(qw, kw, f1w, f2w, qwP, kwP, f1P, f2P,
                                       istyle, style_w, style_b, styleb);
  wnorm2_kernel<<<128, 256, 0, stream>>>(conv1_w, conv2_w, wb1, wb2);
  up2t_kernel<<<dim3(128, NB), 256, 0, stream>>>(x, xupT);
  nzt_kernel<<<dim3(64, NB, 2), 256, 0, stream>>>(noise1, noise2, nzP);

  // attention path for BOTH noises, bi-major grids for weight-set locality
  pk_kernel<<<dim3(8, 128), 256, 0, stream>>>(noise1, noise2, nzP, kwP, Gpartb);
  gsum_kernel<<<160, 256, 0, stream>>>(Gpartb, Gsum);
  ctxM_kernel<<<dim3(16, NB, 2), 256, 0, stream>>>(Gsum, vw, ow, MtP);
  attnd4_kernel<<<dim3(8, 256), 256, 0, stream>>>(nzP, qwP, MtP, ob, ga,
                                                  f1P, f1b, f2P, f2b, gf, nbufP);

  // conv chain (dependent, stays serial)
  convmfma_kernel<<<dim3(2, 128, NB), 256, 0, stream>>>(
      xupT, 128, wb1, nbufP, nullptr, xaT, nullptr, nullptr, nullptr, nullptr);
  convmfma_kernel<<<dim3(2, 128, NB), 256, 0, stream>>>(
      xaT, 64, wb2, nbufP + 4194304L, out_x, nullptr, rgb_w, styleb, prev_rgb, rgbs);

  upblur_kernel<<<dim3(256, 12), 256, 0, stream>>>(rgbs, out_rgb);
}

// Round 11
// 279.996 us; speedup vs baseline: 1.0645x; 1.0645x over previous
//
#include <hip/hip_runtime.h>
#include <math.h>

#define NB 4
#define NF 64
#define NPIX 16384
#define DK 256
#define DV 512
#define QKSCALE 0.4204482f

typedef __attribute__((ext_vector_type(8))) short bf16x8;
typedef __attribute__((ext_vector_type(4))) float f32x4;
#define MFMA16(a, b, c) __builtin_amdgcn_mfma_f32_16x16x32_bf16(a, b, c, 0, 0, 0)

// hardware bf16 convert (v_cvt_pk_bf16_f32, RNE) -- bit-identical to software RNE.
__device__ __forceinline__ short f2bf(float f) {
  __bf16 h = (__bf16)f;
  return __builtin_bit_cast(short, h);
}
__device__ __forceinline__ float bf2f(short s) {
  unsigned u = ((unsigned)(unsigned short)s) << 16;
  return __builtin_bit_cast(float, u);
}

// workspace offsets (float units)
#define OFF_XUPT   0L          // bf16 [4][128y][128x][128c]  4,194,304 f
#define OFF_XAT    4194304L    // bf16 [4][128y][128x][64c]   2,097,152 f
#define OFF_NBT    6291456L    // bf16 frag-packed [8bi][1024nt][4ct][64lane][4]  4,194,304 f
#define OFF_NZT    10485760L   // bf16 frag-packed [8bi][1024nt][2ks][64lane][8]  4,194,304 f
#define OFF_GPART  14680064L   // bf16 [8bi][128ch][256][80] 10,485,760 f
#define OFF_WB1    25165824L   // bf16 frag-packed [9sh][4ct][4ks][512]  36,864 f
#define OFF_WB2    25202688L   // bf16 frag-packed [9sh][4ct][2ks][512]  18,432 f
#define OFF_STYLE  25221120L   // [4][64] fp32                      256
#define OFF_RGBS   25221376L   // [4][3][128][128] fp32         196,608
#define OFF_QWB    25417984L   // bf16 frag-packed [2][16hd][2ks][512]   16,384 f
#define OFF_KWB    25434368L   // bf16 frag-packed [2][4q][4dt][2ks][512] 16,384 f
#define OFF_F1WB   25450752L   // bf16 frag-packed [2][8jt][2ks][512]     8,192 f
#define OFF_F2WB   25458944L   // bf16 frag-packed [2][4ct][2p][2ks][512] 8,192 f
#define OFF_MTT    25467136L   // bf16 frag-packed [8bi][4ct][8h][512]   65,536 f
#define OFF_GSUM   25532672L   // fp32 [8bi][256][80]           163,840 f
// total 25,696,512 floats = 102.8 MB

#define CDIV(a,b) (((a)+(b)-1)/(b))

// ---------------- fused prep: cvt4+style (0..384), wnorm2 (385..512), up2t (513..1024) ---
__global__ __launch_bounds__(256) void prep_kernel(
    const float* __restrict__ qw, const float* __restrict__ kw,
    const float* __restrict__ f1w, const float* __restrict__ f2w,
    short* __restrict__ qwP, short* __restrict__ kwP,
    short* __restrict__ f1P, short* __restrict__ f2P,
    const float* __restrict__ istyle, const float* __restrict__ sw,
    const float* __restrict__ sb, float* __restrict__ styleb,
    const float* __restrict__ W1, const float* __restrict__ W2,
    short* __restrict__ wb1, short* __restrict__ wb2,
    const float* __restrict__ xin, short* __restrict__ xupT) {
  __shared__ float shmem[64 * 132];
  int bid = blockIdx.x;
  int tid = threadIdx.x;
  if (bid < 384) {   // cvt4: fp32 -> bf16 fragment-packed attn weights
    int i = bid * 256 + tid;   // 98304 total
    if (i < 32768) {
      int i_t = i >> 14, rem = i & 16383;
      int hd = rem >> 10, ks = (rem >> 9) & 1, lane = (rem >> 3) & 63, j = rem & 7;
      int l15 = lane & 15, quad = lane >> 4;
      qwP[i] = f2bf(qw[i_t * 16384 + (hd * 16 + l15) * 64 + ks * 32 + quad * 8 + j]);
    } else if (i < 65536) {
      int ii = i - 32768;
      int i_t = ii >> 14, rem = ii & 16383;
      int q = rem >> 12, dt = (rem >> 10) & 3, ks = (rem >> 9) & 1, lane = (rem >> 3) & 63, j = rem & 7;
      int l15 = lane & 15, quad = lane >> 4;
      kwP[ii] = f2bf(kw[i_t * 16384 + (q * 64 + dt * 16 + l15) * 64 + ks * 32 + quad * 8 + j]);
    } else if (i < 81920) {
      int ii = i - 65536;
      int i_t = ii >> 13, rem = ii & 8191;
      int jt = rem >> 10, ks = (rem >> 9) & 1, lane = (rem >> 3) & 63, j = rem & 7;
      int l15 = lane & 15, quad = lane >> 4;
      f1P[ii] = f2bf(f1w[i_t * 8192 + (jt * 16 + l15) * 64 + ks * 32 + quad * 8 + j]);
    } else {
      int ii = i - 81920;
      int i_t = ii >> 13, rem = ii & 8191;
      int ct = rem >> 11, p = (rem >> 10) & 1, ks = (rem >> 9) & 1, lane = (rem >> 3) & 63, j = rem & 7;
      int l15 = lane & 15, quad = lane >> 4;
      f2P[ii] = f2bf(f2w[i_t * 8192 + (ct * 16 + l15) * 128 + p * 64 + ks * 32 + quad * 8 + j]);
    }
    return;
  }
  if (bid == 384) {   // style
    int b = tid >> 6;
    int c = tid & 63;
    float a = 0.f;
    const float* ip = istyle + b * 512;
    const float* wp = sw + c * 512;
    for (int l = 0; l < 512; ++l) a += ip[l] * wp[l];
    styleb[b * 64 + c] = a + sb[c];
    return;
  }
  if (bid < 513) {   // wnorm: demod weight prep -> frag-packed
    int wb_ = bid - 385;
    int which = wb_ >> 6;
    int co = wb_ & 63;
    const float* W = which ? W2 : W1;
    short* wbP = which ? wb2 : wb1;
    int CI = which ? 64 : 128;
    int n = CI * 9;
    int KS = CI >> 5;
    float* red = shmem;
    float s = 0.f;
    for (int idx = tid; idx < n; idx += 256) {
      float w2 = 2.0f * W[co * n + idx];
      s += w2 * w2;
    }
    red[tid] = s;
    __syncthreads();
    for (int off = 128; off > 0; off >>= 1) {
      if (tid < off) red[tid] += red[tid + off];
      __syncthreads();
    }
    float sc = rsqrtf(red[0] + 1e-8f);
    int ct = co >> 4, l15 = co & 15;
    for (int idx = tid; idx < n; idx += 256) {
      int ci = idx / 9, k = idx - ci * 9;
      int ks = ci >> 5, quad = (ci >> 3) & 3, j = ci & 7;
      wbP[((k * 4 + ct) * KS + ks) * 512 + (quad * 16 + l15) * 8 + j] =
          f2bf(2.0f * W[co * n + idx] * sc);
    }
    return;
  }
  // up2t: fused bilinear up2 + NCHW->NHWC bf16, coalesced stores
  int idx0 = bid - 513;
  int b = idx0 >> 7, y = idx0 & 127;
  int w = tid >> 6, lane = tid & 63, quad = lane >> 4, l15 = lane & 15;
  float* row = shmem;   // [xin64][c pad132]
  float iy = y * 0.5f - 0.25f;
  int y0 = (int)floorf(iy); float wy = iy - (float)y0;
  int ylo = y0 < 0 ? 0 : y0;
  int yhi = y0 + 1 > 63 ? 63 : y0 + 1;
  for (int it = 0; it < 32; ++it) {
    int idx = it * 256 + tid;
    int c = idx >> 6, xi = idx & 63;
    const float* bp = xin + ((long)(b * 128 + c)) * 4096;
    float v0 = bp[ylo * 64 + xi];
    float v1 = bp[yhi * 64 + xi];
    row[xi * 132 + c] = (1.f - wy) * v0 + wy * v1;
  }
  __syncthreads();
  long ybase = (((long)(b * 128 + y)) * 128) * 128;
#pragma unroll
  for (int s = 0; s < 8; ++s) {
    int x = w * 32 + s * 4 + quad;
    float ix = x * 0.5f - 0.25f;
    int x0 = (int)floorf(ix); float wx = ix - (float)x0;
    int xlo = x0 < 0 ? 0 : x0;
    int xhi = x0 + 1 > 63 ? 63 : x0 + 1;
    bf16x8 pack;
#pragma unroll
    for (int j = 0; j < 8; ++j) {
      int c = l15 * 8 + j;
      float v = (1.f - wx) * row[xlo * 132 + c] + wx * row[xhi * 132 + c];
      pack[j] = f2bf(v);
    }
    *(bf16x8*)(xupT + ybase + (long)x * 128 + l15 * 8) = pack;
  }
}

// ---------------- pk: Gpart = exp(kw@X) @ [X^T | 1 | 0]; ALSO packs nzP fragments --------
// grid (8 bi, 128 ch). Each block stages X once (float4), emits the 16 nzP fragments
// for its 128-px chunk (replaces the old nzt kernel), and builds its own B-fragments
// from LDS. Values bit-identical to the old nzt path (same f2bf of same floats).
__global__ __launch_bounds__(256, 4) void pk_kernel(const float* __restrict__ nz1,
                                                    const float* __restrict__ nz2,
                                                    short* __restrict__ nzP,
                                                    const short* __restrict__ kwP,
                                                    short* __restrict__ Gpartb) {
  __shared__ __attribute__((aligned(16))) char lds[39168];
  int bi = blockIdx.x, ch = blockIdx.y;
  int i = bi >> 2, b = bi & 3;
  const float* nz = (i == 0) ? nz1 : nz2;
  const short* kwP_i = kwP + i * (DK * NF);
  int tid = threadIdx.x;
  int w = tid >> 6, lane = tid & 63, quad = lane >> 4, l15 = lane & 15;
  int n0 = ch * 128;
  short* Xb = (short*)lds;               // [80][136]
  short* Ph = (short*)(lds + 21760);     // [64][136]
  // float4 staging: wave = 2 c-rows x 512B contiguous
#pragma unroll
  for (int k = 0; k < 8; ++k) {
    int idx = tid + k * 256;
    int c = idx >> 5, g = idx & 31;
    float4 v = *(const float4*)(nz + ((long)b * 64 + c) * NPIX + n0 + g * 4);
    short* xp = Xb + c * 136 + g * 4;
    xp[0] = f2bf(v.x); xp[1] = f2bf(v.y); xp[2] = f2bf(v.z); xp[3] = f2bf(v.w);
  }
  for (int k = 0; k < 8; ++k) {
    int idx = tid + k * 256;
    int c = 64 + (idx >> 7), n = idx & 127;
    Xb[c * 136 + n] = (c == 64) ? (short)0x3F80 : (short)0;
  }
  __syncthreads();
  // pack the 16 nzP fragments (8 ntiles x 2 ks) for this 128-px chunk: 1024 slots
  long fragb = (long)bi * 1024 + ch * 8;
#pragma unroll
  for (int v = 0; v < 4; ++v) {
    int slot = tid + v * 256;
    int frag = slot >> 6, ln = slot & 63;
    int nt = frag >> 1, ksf = frag & 1;
    int fl15 = ln & 15, fq = ln >> 4;
    bf16x8 pack;
#pragma unroll
    for (int j = 0; j < 8; ++j)
      pack[j] = Xb[(ksf * 32 + fq * 8 + j) * 136 + nt * 16 + fl15];
    *(bf16x8*)(nzP + ((fragb + nt) * 2 + ksf) * 512 + ln * 8) = pack;
  }
  // build this wave's B fragments from Xb (same values as old nzP global loads)
  bf16x8 bfr[2][2];
#pragma unroll
  for (int j = 0; j < 2; ++j)
#pragma unroll
    for (int ks = 0; ks < 2; ++ks)
#pragma unroll
      for (int jj = 0; jj < 8; ++jj)
        bfr[j][ks][jj] = Xb[(ks * 32 + quad * 8 + jj) * 136 + (2 * w + j) * 16 + l15];
  for (int q = 0; q < 4; ++q) {
    f32x4 acc[2][4];
#pragma unroll
    for (int j = 0; j < 2; ++j)
#pragma unroll
      for (int dt = 0; dt < 4; ++dt) acc[j][dt] = (f32x4){0.f, 0.f, 0.f, 0.f};
#pragma unroll
    for (int j = 0; j < 2; ++j) {
#pragma unroll
      for (int ks = 0; ks < 2; ++ks) {
#pragma unroll
        for (int dt = 0; dt < 4; ++dt) {
          bf16x8 afr = *(const bf16x8*)(kwP_i + (((q * 4 + dt) * 2 + ks) * 512 + lane * 8));
          acc[j][dt] = MFMA16(afr, bfr[j][ks], acc[j][dt]);
        }
      }
    }
#pragma unroll
    for (int j = 0; j < 2; ++j) {
      int ntile = 2 * w + j;
#pragma unroll
      for (int dt = 0; dt < 4; ++dt)
#pragma unroll
        for (int r = 0; r < 4; ++r) {
          float p = __expf(acc[j][dt][r] * QKSCALE);
          Ph[(dt * 16 + quad * 4 + r) * 136 + ntile * 16 + l15] = f2bf(p);
        }
    }
    __syncthreads();
#pragma unroll
    for (int ct = 0; ct < 5; ++ct) {
      f32x4 g = (f32x4){0.f, 0.f, 0.f, 0.f};
#pragma unroll
      for (int ks = 0; ks < 4; ++ks) {
        bf16x8 afr = *(const bf16x8*)(Ph + (w * 16 + l15) * 136 + ks * 32 + quad * 8);
        bf16x8 bfr2 = *(const bf16x8*)(Xb + (ct * 16 + l15) * 136 + ks * 32 + quad * 8);
        g = MFMA16(afr, bfr2, g);
      }
#pragma unroll
      for (int r = 0; r < 4; ++r) {
        int row = q * 64 + w * 16 + quad * 4 + r;
        Gpartb[(((long)bi * 128 + ch) * 256 + row) * 80 + ct * 16 + l15] = f2bf(g[r]);
      }
    }
    __syncthreads();
  }
}

// ---------------- gsum: reduce Gpart over ch -> Gsum fp32 [bi][256][80], short4/lane -----
// 20480 elems/bi = 5120 groups-of-4; total 8*5120 = 40960 = 160 blocks x 256.
__global__ __launch_bounds__(256) void gsum_kernel(const short* __restrict__ Gpartb,
                                                   float* __restrict__ Gsum) {
  int idx4 = blockIdx.x * 256 + threadIdx.x;   // 40960 total
  int bi = idx4 / 5120;
  int rem4 = idx4 - bi * 5120;
  const short* gp = Gpartb + (long)bi * 128 * 20480 + rem4 * 4;
  float a0 = 0.f, a1 = 0.f, a2 = 0.f, a3 = 0.f;
#pragma unroll 8
  for (int ch = 0; ch < 128; ++ch) {
    short4 v = *(const short4*)(gp + (long)ch * 20480);
    a0 += bf2f(v.x); a1 += bf2f(v.y); a2 += bf2f(v.z); a3 += bf2f(v.w);
  }
  float4 o = {a0, a1, a2, a3};
  *(float4*)(Gsum + (long)bi * 20480 + rem4 * 4) = o;
}

// ---------------- ctxM: Gsum -> ctx -> MtP (fragment-packed) -----------------------------
__global__ __launch_bounds__(256) void ctxM_kernel(const float* __restrict__ Gsum,
                                                   const float* __restrict__ vw,
                                                   const float* __restrict__ ow,
                                                   short* __restrict__ MtP) {
  int i = blockIdx.z, b = blockIdx.y, dt = blockIdx.x * 16;
  int h = dt >> 5;
  __shared__ float Gs[16][81];
  __shared__ float ctxs[16][68];
  int t = threadIdx.x;
  const float* gsb = Gsum + ((long)(i * NB + b)) * 20480;
  for (int idx = t; idx < 1280; idx += 256) {
    int dl = idx / 80, c = idx - dl * 80;
    Gs[dl][c] = gsb[(dt + dl) * 80 + c];
  }
  __syncthreads();
  const float* vw_i = vw + (long)i * DV * NF;
  const float* ow_i = ow + (long)i * NF * DV;
  for (int idx = t; idx < 1024; idx += 256) {
    int dl = idx & 15, e = idx >> 4;
    const float* vp = vw_i + (h * 64 + e) * 64;
    float a = 0.f;
#pragma unroll
    for (int c = 0; c < 64; ++c) a += Gs[dl][c] * vp[c];
    ctxs[dl][e] = a / Gs[dl][64];
  }
  __syncthreads();
  // MtP[bi][ct4][h8][lane][8] = MtT[c=ct*16+l15][d=h*32+quad*8+r]
  short* mtp = MtP + ((long)(i * NB + b)) * 16384;
  for (int idx = t; idx < 1024; idx += 256) {
    int dl = idx & 15, c = idx >> 4;
    const float* op = ow_i + c * 512 + h * 64;
    float a = 0.f;
#pragma unroll
    for (int e = 0; e < 64; ++e) a += op[e] * ctxs[dl][e];
    int d = dt + dl;
    int ct = c >> 4, l15 = c & 15, hh = d >> 5, quad = (d >> 3) & 3, r = d & 7;
    mtp[((ct * 8 + hh) * 64 + quad * 16 + l15) * 8 + r] = f2bf(a);
  }
}

// ---------------- attnd4: fused attn+FF, bi-major grid for weight-set locality -----------
// grid (8 bi, 256 x), block 256 = 4 waves, 16 px/wave. Per-wave LDS 4096 B.
// launch_bounds (256,6): (256,8) raised occupancy 44->63% but doubled HBM traffic
// (FETCH 8.7->19.1 MB, WRITE 16.4->38.7 MB) and was net slower -- keep 6.
__global__ __launch_bounds__(256, 6) void attnd4_kernel(
    const short* __restrict__ nzP, const short* __restrict__ qwP,
    const short* __restrict__ MtP, const float* __restrict__ ob,
    const float* __restrict__ gap, const short* __restrict__ f1P,
    const float* __restrict__ f1b, const short* __restrict__ f2P,
    const float* __restrict__ f2b, const float* __restrict__ gfp,
    short* __restrict__ noutP) {
  __shared__ __attribute__((aligned(16))) short lds[4 * 2048];
  int bi = blockIdx.x;
  int i = bi >> 2;
  int tid = threadIdx.x;
  int w = tid >> 6, lane = tid & 63, quad = lane >> 4, l15 = lane & 15;
  short* Xt = lds + w * 2048;     // [16][72]
  short* Es = Xt + 1152;          // [16][56]
  float ga = gap[i], gf = gfp[i];
  const short* qwP_i = qwP + i * (DK * NF);
  const short* f1P_i = f1P + i * (128 * 64);
  const float* f1b_i = f1b + i * 128;
  const short* f2P_i = f2P + i * (64 * 128);
  const float* f2b_i = f2b + i * 64;
  const float* ob_i = ob + i * 64;
  long ntile = (long)bi * 1024 + blockIdx.y * 4 + w;
  // stage X: two fully-coalesced 1KB fragment loads, mirror into LDS for residual
  const short* nb = nzP + ntile * 1024;
  bf16x8 xfr0 = *(const bf16x8*)(nb + lane * 8);
  bf16x8 xfr1 = *(const bf16x8*)(nb + 512 + lane * 8);
  *(bf16x8*)(Xt + l15 * 72 + quad * 8) = xfr0;
  *(bf16x8*)(Xt + l15 * 72 + 32 + quad * 8) = xfr1;
  const short* mtp = MtP + (long)bi * 16384;
  f32x4 acc2[4];
#pragma unroll
  for (int ct = 0; ct < 4; ++ct) acc2[ct] = (f32x4){0.f, 0.f, 0.f, 0.f};
  // per-head: GEMM1 (q) -> softmax -> E-strip -> GEMM2 chunk
#pragma unroll
  for (int h = 0; h < 8; ++h) {
    f32x4 q[2];
#pragma unroll
    for (int dd = 0; dd < 2; ++dd) {
      int hd = 2 * h + dd;
      q[dd] = (f32x4){0.f, 0.f, 0.f, 0.f};
      bf16x8 a0 = *(const bf16x8*)(qwP_i + (hd * 2 + 0) * 512 + lane * 8);
      q[dd] = MFMA16(a0, xfr0, q[dd]);
      bf16x8 a1 = *(const bf16x8*)(qwP_i + (hd * 2 + 1) * 512 + lane * 8);
      q[dd] = MFMA16(a1, xfr1, q[dd]);
    }
    float part = 0.f;
#pragma unroll
    for (int dd = 0; dd < 2; ++dd)
#pragma unroll
      for (int r = 0; r < 4; ++r) {
        float e = __expf(q[dd][r] * QKSCALE);
        q[dd][r] = e;
        part += e;
      }
    float p2 = part + __shfl_xor(part, 16);
    float s = p2 + __shfl_xor(p2, 32);
    float inv = 1.0f / s;
#pragma unroll
    for (int dd = 0; dd < 2; ++dd) {
      short4 ev;
      ev.x = f2bf(q[dd][0] * inv); ev.y = f2bf(q[dd][1] * inv);
      ev.z = f2bf(q[dd][2] * inv); ev.w = f2bf(q[dd][3] * inv);
      *(short4*)(Es + l15 * 56 + dd * 16 + quad * 4) = ev;
    }
    bf16x8 efr = *(const bf16x8*)(Es + l15 * 56 + quad * 8);
#pragma unroll
    for (int ct = 0; ct < 4; ++ct) {
      bf16x8 afr = *(const bf16x8*)(mtp + (ct * 8 + h) * 512 + lane * 8);
      acc2[ct] = MFMA16(afr, efr, acc2[ct]);
    }
  }
  // residual y = x + ga*(o + ob): x from LDS bf16, y back to Xt + fp32 regs
  float yreg[4][4];
#pragma unroll
  for (int ct = 0; ct < 4; ++ct) {
    int c0 = ct * 16 + quad * 4;
    short4 xs = *(const short4*)(Xt + l15 * 72 + c0);
    float xv[4] = {bf2f(xs.x), bf2f(xs.y), bf2f(xs.z), bf2f(xs.w)};
    short4 ys;
#pragma unroll
    for (int r = 0; r < 4; ++r) yreg[ct][r] = xv[r] + ga * (acc2[ct][r] + ob_i[c0 + r]);
    ys.x = f2bf(yreg[ct][0]); ys.y = f2bf(yreg[ct][1]);
    ys.z = f2bf(yreg[ct][2]); ys.w = f2bf(yreg[ct][3]);
    *(short4*)(Xt + l15 * 72 + c0) = ys;
  }
  bf16x8 yfr0 = *(const bf16x8*)(Xt + l15 * 72 + quad * 8);
  bf16x8 yfr1 = *(const bf16x8*)(Xt + l15 * 72 + 32 + quad * 8);
  // GEMM3: h1[128j x 16n]
  f32x4 acc3[8];
#pragma unroll
  for (int jt = 0; jt < 8; ++jt) {
    acc3[jt] = (f32x4){0.f, 0.f, 0.f, 0.f};
    bf16x8 a0 = *(const bf16x8*)(f1P_i + (jt * 2 + 0) * 512 + lane * 8);
    acc3[jt] = MFMA16(a0, yfr0, acc3[jt]);
    bf16x8 a1 = *(const bf16x8*)(f1P_i + (jt * 2 + 1) * 512 + lane * 8);
    acc3[jt] = MFMA16(a1, yfr1, acc3[jt]);
  }
  // GEMM4 in 2 chunks of 64 j through the Xt strip
  f32x4 acc4[4];
#pragma unroll
  for (int ct = 0; ct < 4; ++ct) acc4[ct] = (f32x4){0.f, 0.f, 0.f, 0.f};
#pragma unroll
  for (int p = 0; p < 2; ++p) {
#pragma unroll
    for (int jj = 0; jj < 4; ++jj) {
      int jt = p * 4 + jj;
      short4 hs;
#pragma unroll
      for (int r = 0; r < 4; ++r) {
        float a = acc3[jt][r] + f1b_i[jt * 16 + quad * 4 + r];
        a = a > 0.f ? a : 0.2f * a;
        ((short*)&hs)[r] = f2bf(a);
      }
      *(short4*)(Xt + l15 * 72 + jj * 16 + quad * 4) = hs;
    }
    bf16x8 h0 = *(const bf16x8*)(Xt + l15 * 72 + quad * 8);
    bf16x8 h1 = *(const bf16x8*)(Xt + l15 * 72 + 32 + quad * 8);
#pragma unroll
    for (int ct = 0; ct < 4; ++ct) {
      bf16x8 a0 = *(const bf16x8*)(f2P_i + ((ct * 2 + p) * 2 + 0) * 512 + lane * 8);
      acc4[ct] = MFMA16(a0, h0, acc4[ct]);
      bf16x8 a1 = *(const bf16x8*)(f2P_i + ((ct * 2 + p) * 2 + 1) * 512 + lane * 8);
      acc4[ct] = MFMA16(a1, h1, acc4[ct]);
    }
  }
  // output fragment-packed: noutP[ntile][ct][lane][4] -- 512B coalesced per store
#pragma unroll
  for (int ct = 0; ct < 4; ++ct) {
    int c0 = ct * 16 + quad * 4;
    short4 ov;
#pragma unroll
    for (int r = 0; r < 4; ++r)
      ((short*)&ov)[r] = f2bf(yreg[ct][r] + gf * (acc4[ct][r] + f2b_i[c0 + r]));
    *(short4*)(noutP + (ntile * 4 + ct) * 256 + lane * 4) = ov;
  }
}

// ---------------- MFMA 3x3 conv: NHWC bf16 in, frag-packed weights+addend, lrelu, +rgb ---
// grid (2 xh, 128 y, NB). wave w -> one 16-px ntile; block covers 64 px (half row).
__global__ __launch_bounds__(256, 4) void convmfma_kernel(
    const short* __restrict__ inT, int CI, const short* __restrict__ wbP,
    const short* __restrict__ addnP, float* __restrict__ out_nchw,
    short* __restrict__ out_nhwc, const float* __restrict__ rgbw,
    const float* __restrict__ styleb, const float* __restrict__ prev,
    float* __restrict__ rgbs) {
  __shared__ __attribute__((aligned(16))) short Bs[3 * 66 * 40];  // [r][xi][ci32 pad40]
  int xh = blockIdx.x, y = blockIdx.y, b = blockIdx.z;
  int tid = threadIdx.x;
  int w = tid >> 6, lane = tid & 63, quad = lane >> 4, l15 = lane & 15;
  int KS = CI >> 5;
  f32x4 acc[4];
#pragma unroll
  for (int ct = 0; ct < 4; ++ct) acc[ct] = (f32x4){0.f, 0.f, 0.f, 0.f};
  for (int ks = 0; ks < KS; ++ks) {
    if (ks) __syncthreads();
    for (int t = tid; t < 792; t += 256) {
      int ci8 = t & 3, xr = t >> 2;
      int xi = xr % 66, r = xr / 66;
      int gy = y + r - 1, gx = xh * 64 + xi - 1;
      bf16x8 v = {0, 0, 0, 0, 0, 0, 0, 0};
      if (gy >= 0 && gy < 128 && gx >= 0 && gx < 128)
        v = *(const bf16x8*)(inT + (((long)(b * 128 + gy)) * 128 + gx) * CI + ks * 32 + ci8 * 8);
      *(bf16x8*)(Bs + (r * 66 + xi) * 40 + ci8 * 8) = v;
    }
    __syncthreads();
#pragma unroll
    for (int sh = 0; sh < 9; ++sh) {
      int dyv = sh / 3, dxv = sh - dyv * 3;
      const short* wbase = wbP + ((sh * 4) * KS + ks) * 512 + lane * 8;
      bf16x8 a0 = *(const bf16x8*)(wbase);
      bf16x8 a1 = *(const bf16x8*)(wbase + KS * 512);
      bf16x8 a2 = *(const bf16x8*)(wbase + 2 * KS * 512);
      bf16x8 a3 = *(const bf16x8*)(wbase + 3 * KS * 512);
      int xi = w * 16 + l15 + dxv;
      bf16x8 bf = *(const bf16x8*)(Bs + (dyv * 66 + xi) * 40 + quad * 8);
      acc[0] = MFMA16(a0, bf, acc[0]);
      acc[1] = MFMA16(a1, bf, acc[1]);
      acc[2] = MFMA16(a2, bf, acc[2]);
      acc[3] = MFMA16(a3, bf, acc[3]);
    }
  }
  // epilogue: lrelu(conv + addn(frag-packed)), stores, optional rgb
  int x = xh * 64 + w * 16 + l15;
  long nidx = ((long)(b * 128 + y)) * 128 + x;
  long ntile = (long)b * 1024 + y * 8 + xh * 4 + w;
  float p0 = 0.f, p1 = 0.f, p2 = 0.f;
#pragma unroll
  for (int ct = 0; ct < 4; ++ct) {
    short4 ad = *(const short4*)(addnP + (ntile * 4 + ct) * 256 + lane * 4);
    float av[4] = {bf2f(ad.x), bf2f(ad.y), bf2f(ad.z), bf2f(ad.w)};
    float v[4];
#pragma unroll
    for (int r = 0; r < 4; ++r) {
      float a = acc[ct][r] + av[r];
      v[r] = a > 0.f ? a : 0.2f * a;
    }
    if (out_nchw) {
#pragma unroll
      for (int r = 0; r < 4; ++r) {
        int co = ct * 16 + quad * 4 + r;
        out_nchw[((long)(b * 64 + co)) * 16384 + y * 128 + x] = v[r];
      }
    }
    if (out_nhwc) {
      short4 pv;
      pv.x = f2bf(v[0]); pv.y = f2bf(v[1]); pv.z = f2bf(v[2]); pv.w = f2bf(v[3]);
      *(short4*)(out_nhwc + nidx * 64 + ct * 16 + quad * 4) = pv;
    }
    if (rgbw) {
#pragma unroll
      for (int r = 0; r < 4; ++r) {
        int co = ct * 16 + quad * 4 + r;
        float mv = (styleb[b * 64 + co] + 1.0f) * v[r];
        p0 += rgbw[co] * mv;
        p1 += rgbw[64 + co] * mv;
        p2 += rgbw[128 + co] * mv;
      }
    }
  }
  if (rgbw) {
    p0 += __shfl_xor(p0, 16); p0 += __shfl_xor(p0, 32);
    p1 += __shfl_xor(p1, 16); p1 += __shfl_xor(p1, 32);
    p2 += __shfl_xor(p2, 16); p2 += __shfl_xor(p2, 32);
    if (quad == 0) {
      long pi = y * 128 + x;
      rgbs[((long)(b * 3 + 0)) * 16384 + pi] = p0 + prev[((long)(b * 3 + 0)) * 16384 + pi];
      rgbs[((long)(b * 3 + 1)) * 16384 + pi] = p1 + prev[((long)(b * 3 + 1)) * 16384 + pi];
      rgbs[((long)(b * 3 + 2)) * 16384 + pi] = p2 + prev[((long)(b * 3 + 2)) * 16384 + pi];
    }
  }
}

// ---------------- fused bilinear up2 + [1,2,1] blur (rgb tail) ---------------------------
__global__ void upblur_kernel(const float* __restrict__ rgbs, float* __restrict__ out) {
  __shared__ float rows[3][128];
  int bc = blockIdx.y, Y = blockIdx.x, X = threadIdx.x;
  int m = Y >> 1;
  const float* base = rgbs + (long)bc * 16384;
  for (int t = X; t < 384; t += 256) {
    int sr = t >> 7, xx = t & 127;
    int rr = m - 1 + sr;
    rr = rr < 0 ? 0 : (rr > 127 ? 127 : rr);
    rows[sr][xx] = base[rr * 128 + xx];
  }
  __syncthreads();
  const float w3[3] = {1.f, 2.f, 1.f};
  float s = 0.f;
#pragma unroll
  for (int dy = -1; dy <= 1; ++dy) {
    int Yv = Y + dy;
    if (Yv < 0 || Yv > 255) continue;
    float iy = Yv * 0.5f - 0.25f;
    int y0 = (int)floorf(iy); float wy = iy - (float)y0;
    int ylo = y0 < 0 ? 0 : y0;
    int yhi = y0 + 1 > 127 ? 127 : y0 + 1;
    int slo = ylo - m + 1, shi = yhi - m + 1;
#pragma unroll
    for (int dx = -1; dx <= 1; ++dx) {
      int Xv = X + dx;
      if (Xv < 0 || Xv > 255) continue;
      float ix = Xv * 0.5f - 0.25f;
      int x0 = (int)floorf(ix); float wx = ix - (float)x0;
      int xlo = x0 < 0 ? 0 : x0;
      int xhi = x0 + 1 > 127 ? 127 : x0 + 1;
      float v = (1.f - wy) * ((1.f - wx) * rows[slo][xlo] + wx * rows[slo][xhi])
              + wy * ((1.f - wx) * rows[shi][xlo] + wx * rows[shi][xhi]);
      s += w3[dy + 1] * w3[dx + 1] * v;
    }
  }
  out[(long)bc * 65536 + Y * 256 + X] = s * (1.0f / 16.0f);
}

extern "C" void kernel_launch(void* const* d_in, const int* in_sizes, int n_in,
                              void* d_out, int out_size, void* d_ws, size_t ws_size,
                              hipStream_t stream) {
  (void)in_sizes; (void)n_in; (void)out_size; (void)ws_size;
  const float* x        = (const float*)d_in[0];
  const float* prev_rgb = (const float*)d_in[1];
  const float* istyle   = (const float*)d_in[2];
  const float* noise1   = (const float*)d_in[3];
  const float* noise2   = (const float*)d_in[4];
  const float* conv1_w  = (const float*)d_in[5];
  const float* conv2_w  = (const float*)d_in[6];
  const float* style_w  = (const float*)d_in[7];
  const float* style_b  = (const float*)d_in[8];
  const float* rgb_w    = (const float*)d_in[9];
  const float* qw       = (const float*)d_in[10];
  const float* kw       = (const float*)d_in[11];
  const float* vw       = (const float*)d_in[12];
  const float* ow       = (const float*)d_in[13];
  const float* ob       = (const float*)d_in[14];
  const float* ga       = (const float*)d_in[15];
  const float* f1w      = (const float*)d_in[16];
  const float* f1b      = (const float*)d_in[17];
  const float* f2w      = (const float*)d_in[18];
  const float* f2b      = (const float*)d_in[19];
  const float* gf       = (const float*)d_in[20];
  float* out_x   = (float*)d_out;
  float* out_rgb = out_x + 4194304;
  float* ws = (float*)d_ws;

  short* xupT   = (short*)(ws + OFF_XUPT);
  short* xaT    = (short*)(ws + OFF_XAT);
  short* nbufP  = (short*)(ws + OFF_NBT);
  short* nzP    = (short*)(ws + OFF_NZT);
  short* Gpartb = (short*)(ws + OFF_GPART);
  short* wb1    = (short*)(ws + OFF_WB1);
  short* wb2    = (short*)(ws + OFF_WB2);
  float* styleb = ws + OFF_STYLE;
  float* rgbs   = ws + OFF_RGBS;
  short* qwP    = (short*)(ws + OFF_QWB);
  short* kwP    = (short*)(ws + OFF_KWB);
  short* f1P    = (short*)(ws + OFF_F1WB);
  short* f2P    = (short*)(ws + OFF_F2WB);
  short* MtP    = (short*)(ws + OFF_MTT);
  float* Gsum   = ws + OFF_GSUM;

  // fused prep: cvt4+style | wnorm2 | up2t (all independent, one launch)
  prep_kernel<<<1025, 256, 0, stream>>>(qw, kw, f1w, f2w, qwP, kwP, f1P, f2P,
                                        istyle, style_w, style_b, styleb,
                                        conv1_w, conv2_w, wb1, wb2, x, xupT);

  // attention path (pk also packs nzP -- replaces old nzt kernel)
  pk_kernel<<<dim3(8, 128), 256, 0, stream>>>(noise1, noise2, nzP, kwP, Gpartb);
  gsum_kernel<<<160, 256, 0, stream>>>(Gpartb, Gsum);
  ctxM_kernel<<<dim3(16, NB, 2), 256, 0, stream>>>(Gsum, vw, ow, MtP);
  attnd4_kernel<<<dim3(8, 256), 256, 0, stream>>>(nzP, qwP, MtP, ob, ga,
                                                  f1P, f1b, f2P, f2b, gf, nbufP);

  // conv chain (dependent, stays serial)
  convmfma_kernel<<<dim3(2, 128, NB), 256, 0, stream>>>(
      xupT, 128, wb1, nbufP, nullptr, xaT, nullptr, nullptr, nullptr, nullptr);
  convmfma_kernel<<<dim3(2, 128, NB), 256, 0, stream>>>(
      xaT, 64, wb2, nbufP + 4194304L, out_x, nullptr, rgb_w, styleb, prev_rgb, rgbs);

  upblur_kernel<<<dim3(256, 12), 256, 0, stream>>>(rgbs, out_rgb);
}

// Round 12
// 269.328 us; speedup vs baseline: 1.1067x; 1.0396x over previous
//
#include <hip/hip_runtime.h>
#include <math.h>

#define NB 4
#define NF 64
#define NPIX 16384
#define DK 256
#define DV 512
#define QKSCALE 0.4204482f

typedef __attribute__((ext_vector_type(8))) short bf16x8;
typedef __attribute__((ext_vector_type(4))) float f32x4;
#define MFMA16(a, b, c) __builtin_amdgcn_mfma_f32_16x16x32_bf16(a, b, c, 0, 0, 0)

// hardware bf16 convert (v_cvt_pk_bf16_f32, RNE) -- bit-identical to software RNE.
__device__ __forceinline__ short f2bf(float f) {
  __bf16 h = (__bf16)f;
  return __builtin_bit_cast(short, h);
}
__device__ __forceinline__ float bf2f(short s) {
  unsigned u = ((unsigned)(unsigned short)s) << 16;
  return __builtin_bit_cast(float, u);
}

// workspace offsets (float units)
#define OFF_XUPT   0L          // bf16 [4][128y][128x][128c]  4,194,304 f
#define OFF_XAT    4194304L    // bf16 [4][128y][128x][64c]   2,097,152 f
#define OFF_NBT    6291456L    // bf16 frag-packed [8bi][1024nt][4ct][64lane][4]  4,194,304 f
#define OFF_NZT    10485760L   // bf16 frag-packed [8bi][1024nt][2ks][64lane][8]  4,194,304 f
#define OFF_GPART  14680064L   // bf16 [8bi][128ch][256][80] 10,485,760 f
#define OFF_WB1    25165824L   // bf16 frag-packed [9sh][4ct][4ks][512]  36,864 f
#define OFF_WB2    25202688L   // bf16 frag-packed [9sh][4ct][2ks][512]  18,432 f
#define OFF_STYLE  25221120L   // [4][64] fp32                      256
#define OFF_RGBS   25221376L   // [4][3][128][128] fp32         196,608
#define OFF_QWB    25417984L   // bf16 frag-packed [2][16hd][2ks][512]   16,384 f
#define OFF_KWB    25434368L   // bf16 frag-packed [2][4q][4dt][2ks][512] 16,384 f
#define OFF_F1WB   25450752L   // bf16 frag-packed [2][8jt][2ks][512]     8,192 f
#define OFF_F2WB   25458944L   // bf16 frag-packed [2][4ct][2p][2ks][512] 8,192 f
#define OFF_MTT    25467136L   // bf16 frag-packed [8bi][4ct][8h][512]   65,536 f
#define OFF_GSUM   25532672L   // fp32 [8bi][256][80]           163,840 f
// total 25,696,512 floats = 102.8 MB

#define CDIV(a,b) (((a)+(b)-1)/(b))

// ---------------- fused prep: cvt4+style (0..384), wnorm2 (385..512), up2t (513..1024) ---
__global__ __launch_bounds__(256) void prep_kernel(
    const float* __restrict__ qw, const float* __restrict__ kw,
    const float* __restrict__ f1w, const float* __restrict__ f2w,
    short* __restrict__ qwP, short* __restrict__ kwP,
    short* __restrict__ f1P, short* __restrict__ f2P,
    const float* __restrict__ istyle, const float* __restrict__ sw,
    const float* __restrict__ sb, float* __restrict__ styleb,
    const float* __restrict__ W1, const float* __restrict__ W2,
    short* __restrict__ wb1, short* __restrict__ wb2,
    const float* __restrict__ xin, short* __restrict__ xupT) {
  __shared__ float shmem[64 * 132];
  int bid = blockIdx.x;
  int tid = threadIdx.x;
  if (bid < 384) {   // cvt4: fp32 -> bf16 fragment-packed attn weights
    int i = bid * 256 + tid;   // 98304 total
    if (i < 32768) {
      int i_t = i >> 14, rem = i & 16383;
      int hd = rem >> 10, ks = (rem >> 9) & 1, lane = (rem >> 3) & 63, j = rem & 7;
      int l15 = lane & 15, quad = lane >> 4;
      qwP[i] = f2bf(qw[i_t * 16384 + (hd * 16 + l15) * 64 + ks * 32 + quad * 8 + j]);
    } else if (i < 65536) {
      int ii = i - 32768;
      int i_t = ii >> 14, rem = ii & 16383;
      int q = rem >> 12, dt = (rem >> 10) & 3, ks = (rem >> 9) & 1, lane = (rem >> 3) & 63, j = rem & 7;
      int l15 = lane & 15, quad = lane >> 4;
      kwP[ii] = f2bf(kw[i_t * 16384 + (q * 64 + dt * 16 + l15) * 64 + ks * 32 + quad * 8 + j]);
    } else if (i < 81920) {
      int ii = i - 65536;
      int i_t = ii >> 13, rem = ii & 8191;
      int jt = rem >> 10, ks = (rem >> 9) & 1, lane = (rem >> 3) & 63, j = rem & 7;
      int l15 = lane & 15, quad = lane >> 4;
      f1P[ii] = f2bf(f1w[i_t * 8192 + (jt * 16 + l15) * 64 + ks * 32 + quad * 8 + j]);
    } else {
      int ii = i - 81920;
      int i_t = ii >> 13, rem = ii & 8191;
      int ct = rem >> 11, p = (rem >> 10) & 1, ks = (rem >> 9) & 1, lane = (rem >> 3) & 63, j = rem & 7;
      int l15 = lane & 15, quad = lane >> 4;
      f2P[ii] = f2bf(f2w[i_t * 8192 + (ct * 16 + l15) * 128 + p * 64 + ks * 32 + quad * 8 + j]);
    }
    return;
  }
  if (bid == 384) {   // style
    int b = tid >> 6;
    int c = tid & 63;
    float a = 0.f;
    const float* ip = istyle + b * 512;
    const float* wp = sw + c * 512;
    for (int l = 0; l < 512; ++l) a += ip[l] * wp[l];
    styleb[b * 64 + c] = a + sb[c];
    return;
  }
  if (bid < 513) {   // wnorm: demod weight prep -> frag-packed
    int wb_ = bid - 385;
    int which = wb_ >> 6;
    int co = wb_ & 63;
    const float* W = which ? W2 : W1;
    short* wbP = which ? wb2 : wb1;
    int CI = which ? 64 : 128;
    int n = CI * 9;
    int KS = CI >> 5;
    float* red = shmem;
    float s = 0.f;
    for (int idx = tid; idx < n; idx += 256) {
      float w2 = 2.0f * W[co * n + idx];
      s += w2 * w2;
    }
    red[tid] = s;
    __syncthreads();
    for (int off = 128; off > 0; off >>= 1) {
      if (tid < off) red[tid] += red[tid + off];
      __syncthreads();
    }
    float sc = rsqrtf(red[0] + 1e-8f);
    int ct = co >> 4, l15 = co & 15;
    for (int idx = tid; idx < n; idx += 256) {
      int ci = idx / 9, k = idx - ci * 9;
      int ks = ci >> 5, quad = (ci >> 3) & 3, j = ci & 7;
      wbP[((k * 4 + ct) * KS + ks) * 512 + (quad * 16 + l15) * 8 + j] =
          f2bf(2.0f * W[co * n + idx] * sc);
    }
    return;
  }
  // up2t: fused bilinear up2 + NCHW->NHWC bf16, coalesced stores
  int idx0 = bid - 513;
  int b = idx0 >> 7, y = idx0 & 127;
  int w = tid >> 6, lane = tid & 63, quad = lane >> 4, l15 = lane & 15;
  float* row = shmem;   // [xin64][c pad132]
  float iy = y * 0.5f - 0.25f;
  int y0 = (int)floorf(iy); float wy = iy - (float)y0;
  int ylo = y0 < 0 ? 0 : y0;
  int yhi = y0 + 1 > 63 ? 63 : y0 + 1;
  for (int it = 0; it < 32; ++it) {
    int idx = it * 256 + tid;
    int c = idx >> 6, xi = idx & 63;
    const float* bp = xin + ((long)(b * 128 + c)) * 4096;
    float v0 = bp[ylo * 64 + xi];
    float v1 = bp[yhi * 64 + xi];
    row[xi * 132 + c] = (1.f - wy) * v0 + wy * v1;
  }
  __syncthreads();
  long ybase = (((long)(b * 128 + y)) * 128) * 128;
#pragma unroll
  for (int s = 0; s < 8; ++s) {
    int x = w * 32 + s * 4 + quad;
    float ix = x * 0.5f - 0.25f;
    int x0 = (int)floorf(ix); float wx = ix - (float)x0;
    int xlo = x0 < 0 ? 0 : x0;
    int xhi = x0 + 1 > 63 ? 63 : x0 + 1;
    bf16x8 pack;
#pragma unroll
    for (int j = 0; j < 8; ++j) {
      int c = l15 * 8 + j;
      float v = (1.f - wx) * row[xlo * 132 + c] + wx * row[xhi * 132 + c];
      pack[j] = f2bf(v);
    }
    *(bf16x8*)(xupT + ybase + (long)x * 128 + l15 * 8) = pack;
  }
}

// ---------------- pk: Gpart = exp(kw@X) @ [X^T | 1 | 0]; ALSO packs nzP fragments --------
// grid (8 bi, 128 ch). Each block stages X once (float4), emits the 16 nzP fragments
// for its 128-px chunk, and builds its own B-fragments from LDS.
__global__ __launch_bounds__(256, 4) void pk_kernel(const float* __restrict__ nz1,
                                                    const float* __restrict__ nz2,
                                                    short* __restrict__ nzP,
                                                    const short* __restrict__ kwP,
                                                    short* __restrict__ Gpartb) {
  __shared__ __attribute__((aligned(16))) char lds[39168];
  int bi = blockIdx.x, ch = blockIdx.y;
  int i = bi >> 2, b = bi & 3;
  const float* nz = (i == 0) ? nz1 : nz2;
  const short* kwP_i = kwP + i * (DK * NF);
  int tid = threadIdx.x;
  int w = tid >> 6, lane = tid & 63, quad = lane >> 4, l15 = lane & 15;
  int n0 = ch * 128;
  short* Xb = (short*)lds;               // [80][136]
  short* Ph = (short*)(lds + 21760);     // [64][136]
  // float4 staging: wave = 2 c-rows x 512B contiguous
#pragma unroll
  for (int k = 0; k < 8; ++k) {
    int idx = tid + k * 256;
    int c = idx >> 5, g = idx & 31;
    float4 v = *(const float4*)(nz + ((long)b * 64 + c) * NPIX + n0 + g * 4);
    short* xp = Xb + c * 136 + g * 4;
    xp[0] = f2bf(v.x); xp[1] = f2bf(v.y); xp[2] = f2bf(v.z); xp[3] = f2bf(v.w);
  }
  for (int k = 0; k < 8; ++k) {
    int idx = tid + k * 256;
    int c = 64 + (idx >> 7), n = idx & 127;
    Xb[c * 136 + n] = (c == 64) ? (short)0x3F80 : (short)0;
  }
  __syncthreads();
  // pack the 16 nzP fragments (8 ntiles x 2 ks) for this 128-px chunk: 1024 slots
  long fragb = (long)bi * 1024 + ch * 8;
#pragma unroll
  for (int v = 0; v < 4; ++v) {
    int slot = tid + v * 256;
    int frag = slot >> 6, ln = slot & 63;
    int nt = frag >> 1, ksf = frag & 1;
    int fl15 = ln & 15, fq = ln >> 4;
    bf16x8 pack;
#pragma unroll
    for (int j = 0; j < 8; ++j)
      pack[j] = Xb[(ksf * 32 + fq * 8 + j) * 136 + nt * 16 + fl15];
    *(bf16x8*)(nzP + ((fragb + nt) * 2 + ksf) * 512 + ln * 8) = pack;
  }
  // build this wave's B fragments from Xb
  bf16x8 bfr[2][2];
#pragma unroll
  for (int j = 0; j < 2; ++j)
#pragma unroll
    for (int ks = 0; ks < 2; ++ks)
#pragma unroll
      for (int jj = 0; jj < 8; ++jj)
        bfr[j][ks][jj] = Xb[(ks * 32 + quad * 8 + jj) * 136 + (2 * w + j) * 16 + l15];
  for (int q = 0; q < 4; ++q) {
    f32x4 acc[2][4];
#pragma unroll
    for (int j = 0; j < 2; ++j)
#pragma unroll
      for (int dt = 0; dt < 4; ++dt) acc[j][dt] = (f32x4){0.f, 0.f, 0.f, 0.f};
#pragma unroll
    for (int j = 0; j < 2; ++j) {
#pragma unroll
      for (int ks = 0; ks < 2; ++ks) {
#pragma unroll
        for (int dt = 0; dt < 4; ++dt) {
          bf16x8 afr = *(const bf16x8*)(kwP_i + (((q * 4 + dt) * 2 + ks) * 512 + lane * 8));
          acc[j][dt] = MFMA16(afr, bfr[j][ks], acc[j][dt]);
        }
      }
    }
#pragma unroll
    for (int j = 0; j < 2; ++j) {
      int ntile = 2 * w + j;
#pragma unroll
      for (int dt = 0; dt < 4; ++dt)
#pragma unroll
        for (int r = 0; r < 4; ++r) {
          float p = __expf(acc[j][dt][r] * QKSCALE);
          Ph[(dt * 16 + quad * 4 + r) * 136 + ntile * 16 + l15] = f2bf(p);
        }
    }
    __syncthreads();
#pragma unroll
    for (int ct = 0; ct < 5; ++ct) {
      f32x4 g = (f32x4){0.f, 0.f, 0.f, 0.f};
#pragma unroll
      for (int ks = 0; ks < 4; ++ks) {
        bf16x8 afr = *(const bf16x8*)(Ph + (w * 16 + l15) * 136 + ks * 32 + quad * 8);
        bf16x8 bfr2 = *(const bf16x8*)(Xb + (ct * 16 + l15) * 136 + ks * 32 + quad * 8);
        g = MFMA16(afr, bfr2, g);
      }
#pragma unroll
      for (int r = 0; r < 4; ++r) {
        int row = q * 64 + w * 16 + quad * 4 + r;
        Gpartb[(((long)bi * 128 + ch) * 256 + row) * 80 + ct * 16 + l15] = f2bf(g[r]);
      }
    }
    __syncthreads();
  }
}

// ---------------- gsum: reduce Gpart over ch -> Gsum fp32 [bi][256][80], short4/lane -----
__global__ __launch_bounds__(256) void gsum_kernel(const short* __restrict__ Gpartb,
                                                   float* __restrict__ Gsum) {
  int idx4 = blockIdx.x * 256 + threadIdx.x;   // 40960 total
  int bi = idx4 / 5120;
  int rem4 = idx4 - bi * 5120;
  const short* gp = Gpartb + (long)bi * 128 * 20480 + rem4 * 4;
  float a0 = 0.f, a1 = 0.f, a2 = 0.f, a3 = 0.f;
#pragma unroll 8
  for (int ch = 0; ch < 128; ++ch) {
    short4 v = *(const short4*)(gp + (long)ch * 20480);
    a0 += bf2f(v.x); a1 += bf2f(v.y); a2 += bf2f(v.z); a3 += bf2f(v.w);
  }
  float4 o = {a0, a1, a2, a3};
  *(float4*)(Gsum + (long)bi * 20480 + rem4 * 4) = o;
}

// ---------------- ctxM: Gsum -> ctx -> MtP (fragment-packed) -----------------------------
__global__ __launch_bounds__(256) void ctxM_kernel(const float* __restrict__ Gsum,
                                                   const float* __restrict__ vw,
                                                   const float* __restrict__ ow,
                                                   short* __restrict__ MtP) {
  int i = blockIdx.z, b = blockIdx.y, dt = blockIdx.x * 16;
  int h = dt >> 5;
  __shared__ float Gs[16][81];
  __shared__ float ctxs[16][68];
  int t = threadIdx.x;
  const float* gsb = Gsum + ((long)(i * NB + b)) * 20480;
  for (int idx = t; idx < 1280; idx += 256) {
    int dl = idx / 80, c = idx - dl * 80;
    Gs[dl][c] = gsb[(dt + dl) * 80 + c];
  }
  __syncthreads();
  const float* vw_i = vw + (long)i * DV * NF;
  const float* ow_i = ow + (long)i * NF * DV;
  for (int idx = t; idx < 1024; idx += 256) {
    int dl = idx & 15, e = idx >> 4;
    const float* vp = vw_i + (h * 64 + e) * 64;
    float a = 0.f;
#pragma unroll
    for (int c = 0; c < 64; ++c) a += Gs[dl][c] * vp[c];
    ctxs[dl][e] = a / Gs[dl][64];
  }
  __syncthreads();
  // MtP[bi][ct4][h8][lane][8] = MtT[c=ct*16+l15][d=h*32+quad*8+r]
  short* mtp = MtP + ((long)(i * NB + b)) * 16384;
  for (int idx = t; idx < 1024; idx += 256) {
    int dl = idx & 15, c = idx >> 4;
    const float* op = ow_i + c * 512 + h * 64;
    float a = 0.f;
#pragma unroll
    for (int e = 0; e < 64; ++e) a += op[e] * ctxs[dl][e];
    int d = dt + dl;
    int ct = c >> 4, l15 = c & 15, hh = d >> 5, quad = (d >> 3) & 3, r = d & 7;
    mtp[((ct * 8 + hh) * 64 + quad * 16 + l15) * 8 + r] = f2bf(a);
  }
}

// ---------------- attnd4: fused attn+FF, software-pipelined A-fragment loads -------------
// grid (8 bi, 256 x), block 256 = 4 waves, 16 px/wave. Per-wave LDS 4096 B.
// launch_bounds (256,5): extra VGPR headroom for the qw prefetch double-buffer
// ((256,8) blew the cache in R7 -- occupancy direction here is DOWN, safe).
__global__ __launch_bounds__(256, 5) void attnd4_kernel(
    const short* __restrict__ nzP, const short* __restrict__ qwP,
    const short* __restrict__ MtP, const float* __restrict__ ob,
    const float* __restrict__ gap, const short* __restrict__ f1P,
    const float* __restrict__ f1b, const short* __restrict__ f2P,
    const float* __restrict__ f2b, const float* __restrict__ gfp,
    short* __restrict__ noutP) {
  __shared__ __attribute__((aligned(16))) short lds[4 * 2048];
  int bi = blockIdx.x;
  int i = bi >> 2;
  int tid = threadIdx.x;
  int w = tid >> 6, lane = tid & 63, quad = lane >> 4, l15 = lane & 15;
  short* Xt = lds + w * 2048;     // [16][72]
  short* Es = Xt + 1152;          // [16][56]
  float ga = gap[i], gf = gfp[i];
  const short* qwP_i = qwP + i * (DK * NF);
  const short* f1P_i = f1P + i * (128 * 64);
  const float* f1b_i = f1b + i * 128;
  const short* f2P_i = f2P + i * (64 * 128);
  const float* f2b_i = f2b + i * 64;
  const float* ob_i = ob + i * 64;
  long ntile = (long)bi * 1024 + blockIdx.y * 4 + w;
  // stage X: two fully-coalesced 1KB fragment loads, mirror into LDS for residual
  const short* nb = nzP + ntile * 1024;
  bf16x8 xfr0 = *(const bf16x8*)(nb + lane * 8);
  bf16x8 xfr1 = *(const bf16x8*)(nb + 512 + lane * 8);
  *(bf16x8*)(Xt + l15 * 72 + quad * 8) = xfr0;
  *(bf16x8*)(Xt + l15 * 72 + 32 + quad * 8) = xfr1;
  const short* mtp = MtP + (long)bi * 16384;
  f32x4 acc2[4];
#pragma unroll
  for (int ct = 0; ct < 4; ++ct) acc2[ct] = (f32x4){0.f, 0.f, 0.f, 0.f};
  // preload head 0's qw fragments
  bf16x8 qa00 = *(const bf16x8*)(qwP_i + 0 * 512 + lane * 8);
  bf16x8 qa01 = *(const bf16x8*)(qwP_i + 1 * 512 + lane * 8);
  bf16x8 qa10 = *(const bf16x8*)(qwP_i + 2 * 512 + lane * 8);
  bf16x8 qa11 = *(const bf16x8*)(qwP_i + 3 * 512 + lane * 8);
  // per-head: GEMM1 (q) -> softmax -> E-strip -> GEMM2 chunk; A-loads pipelined
#pragma unroll
  for (int h = 0; h < 8; ++h) {
    // issue this head's mtp fragment loads NOW (latency hides under softmax)
    bf16x8 m0 = *(const bf16x8*)(mtp + (0 * 8 + h) * 512 + lane * 8);
    bf16x8 m1 = *(const bf16x8*)(mtp + (1 * 8 + h) * 512 + lane * 8);
    bf16x8 m2 = *(const bf16x8*)(mtp + (2 * 8 + h) * 512 + lane * 8);
    bf16x8 m3 = *(const bf16x8*)(mtp + (3 * 8 + h) * 512 + lane * 8);
    f32x4 q[2];
    q[0] = (f32x4){0.f, 0.f, 0.f, 0.f};
    q[0] = MFMA16(qa00, xfr0, q[0]);
    q[0] = MFMA16(qa01, xfr1, q[0]);
    q[1] = (f32x4){0.f, 0.f, 0.f, 0.f};
    q[1] = MFMA16(qa10, xfr0, q[1]);
    q[1] = MFMA16(qa11, xfr1, q[1]);
    // prefetch next head's qw fragments (in flight during softmax + GEMM2)
    if (h < 7) {
      int hn = 2 * (h + 1);
      qa00 = *(const bf16x8*)(qwP_i + (hn * 2 + 0) * 512 + lane * 8);
      qa01 = *(const bf16x8*)(qwP_i + (hn * 2 + 1) * 512 + lane * 8);
      qa10 = *(const bf16x8*)(qwP_i + ((hn + 1) * 2 + 0) * 512 + lane * 8);
      qa11 = *(const bf16x8*)(qwP_i + ((hn + 1) * 2 + 1) * 512 + lane * 8);
    }
    float part = 0.f;
#pragma unroll
    for (int dd = 0; dd < 2; ++dd)
#pragma unroll
      for (int r = 0; r < 4; ++r) {
        float e = __expf(q[dd][r] * QKSCALE);
        q[dd][r] = e;
        part += e;
      }
    float p2 = part + __shfl_xor(part, 16);
    float s = p2 + __shfl_xor(p2, 32);
    float inv = 1.0f / s;
#pragma unroll
    for (int dd = 0; dd < 2; ++dd) {
      short4 ev;
      ev.x = f2bf(q[dd][0] * inv); ev.y = f2bf(q[dd][1] * inv);
      ev.z = f2bf(q[dd][2] * inv); ev.w = f2bf(q[dd][3] * inv);
      *(short4*)(Es + l15 * 56 + dd * 16 + quad * 4) = ev;
    }
    bf16x8 efr = *(const bf16x8*)(Es + l15 * 56 + quad * 8);
    acc2[0] = MFMA16(m0, efr, acc2[0]);
    acc2[1] = MFMA16(m1, efr, acc2[1]);
    acc2[2] = MFMA16(m2, efr, acc2[2]);
    acc2[3] = MFMA16(m3, efr, acc2[3]);
  }
  // residual y = x + ga*(o + ob): x from LDS bf16, y back to Xt + fp32 regs
  float yreg[4][4];
#pragma unroll
  for (int ct = 0; ct < 4; ++ct) {
    int c0 = ct * 16 + quad * 4;
    short4 xs = *(const short4*)(Xt + l15 * 72 + c0);
    float xv[4] = {bf2f(xs.x), bf2f(xs.y), bf2f(xs.z), bf2f(xs.w)};
    short4 ys;
#pragma unroll
    for (int r = 0; r < 4; ++r) yreg[ct][r] = xv[r] + ga * (acc2[ct][r] + ob_i[c0 + r]);
    ys.x = f2bf(yreg[ct][0]); ys.y = f2bf(yreg[ct][1]);
    ys.z = f2bf(yreg[ct][2]); ys.w = f2bf(yreg[ct][3]);
    *(short4*)(Xt + l15 * 72 + c0) = ys;
  }
  bf16x8 yfr0 = *(const bf16x8*)(Xt + l15 * 72 + quad * 8);
  bf16x8 yfr1 = *(const bf16x8*)(Xt + l15 * 72 + 32 + quad * 8);
  // GEMM3: h1[128j x 16n]
  f32x4 acc3[8];
#pragma unroll
  for (int jt = 0; jt < 8; ++jt) {
    acc3[jt] = (f32x4){0.f, 0.f, 0.f, 0.f};
    bf16x8 a0 = *(const bf16x8*)(f1P_i + (jt * 2 + 0) * 512 + lane * 8);
    acc3[jt] = MFMA16(a0, yfr0, acc3[jt]);
    bf16x8 a1 = *(const bf16x8*)(f1P_i + (jt * 2 + 1) * 512 + lane * 8);
    acc3[jt] = MFMA16(a1, yfr1, acc3[jt]);
  }
  // GEMM4 in 2 chunks of 64 j through the Xt strip
  f32x4 acc4[4];
#pragma unroll
  for (int ct = 0; ct < 4; ++ct) acc4[ct] = (f32x4){0.f, 0.f, 0.f, 0.f};
#pragma unroll
  for (int p = 0; p < 2; ++p) {
#pragma unroll
    for (int jj = 0; jj < 4; ++jj) {
      int jt = p * 4 + jj;
      short4 hs;
#pragma unroll
      for (int r = 0; r < 4; ++r) {
        float a = acc3[jt][r] + f1b_i[jt * 16 + quad * 4 + r];
        a = a > 0.f ? a : 0.2f * a;
        ((short*)&hs)[r] = f2bf(a);
      }
      *(short4*)(Xt + l15 * 72 + jj * 16 + quad * 4) = hs;
    }
    bf16x8 h0 = *(const bf16x8*)(Xt + l15 * 72 + quad * 8);
    bf16x8 h1 = *(const bf16x8*)(Xt + l15 * 72 + 32 + quad * 8);
#pragma unroll
    for (int ct = 0; ct < 4; ++ct) {
      bf16x8 a0 = *(const bf16x8*)(f2P_i + ((ct * 2 + p) * 2 + 0) * 512 + lane * 8);
      acc4[ct] = MFMA16(a0, h0, acc4[ct]);
      bf16x8 a1 = *(const bf16x8*)(f2P_i + ((ct * 2 + p) * 2 + 1) * 512 + lane * 8);
      acc4[ct] = MFMA16(a1, h1, acc4[ct]);
    }
  }
  // output fragment-packed: noutP[ntile][ct][lane][4] -- 512B coalesced per store
#pragma unroll
  for (int ct = 0; ct < 4; ++ct) {
    int c0 = ct * 16 + quad * 4;
    short4 ov;
#pragma unroll
    for (int r = 0; r < 4; ++r)
      ((short*)&ov)[r] = f2bf(yreg[ct][r] + gf * (acc4[ct][r] + f2b_i[c0 + r]));
    *(short4*)(noutP + (ntile * 4 + ct) * 256 + lane * 4) = ov;
  }
}

// ---------------- MFMA 3x3 conv: NHWC bf16 in, frag-packed weights+addend, lrelu, +rgb ---
// grid (2 xh, 128 y, NB). wave w -> one 16-px ntile; block covers 64 px (half row).
__global__ __launch_bounds__(256, 4) void convmfma_kernel(
    const short* __restrict__ inT, int CI, const short* __restrict__ wbP,
    const short* __restrict__ addnP, float* __restrict__ out_nchw,
    short* __restrict__ out_nhwc, const float* __restrict__ rgbw,
    const float* __restrict__ styleb, const float* __restrict__ prev,
    float* __restrict__ rgbs) {
  __shared__ __attribute__((aligned(16))) short Bs[3 * 66 * 40];  // [r][xi][ci32 pad40]
  int xh = blockIdx.x, y = blockIdx.y, b = blockIdx.z;
  int tid = threadIdx.x;
  int w = tid >> 6, lane = tid & 63, quad = lane >> 4, l15 = lane & 15;
  int KS = CI >> 5;
  f32x4 acc[4];
#pragma unroll
  for (int ct = 0; ct < 4; ++ct) acc[ct] = (f32x4){0.f, 0.f, 0.f, 0.f};
  for (int ks = 0; ks < KS; ++ks) {
    if (ks) __syncthreads();
    for (int t = tid; t < 792; t += 256) {
      int ci8 = t & 3, xr = t >> 2;
      int xi = xr % 66, r = xr / 66;
      int gy = y + r - 1, gx = xh * 64 + xi - 1;
      bf16x8 v = {0, 0, 0, 0, 0, 0, 0, 0};
      if (gy >= 0 && gy < 128 && gx >= 0 && gx < 128)
        v = *(const bf16x8*)(inT + (((long)(b * 128 + gy)) * 128 + gx) * CI + ks * 32 + ci8 * 8);
      *(bf16x8*)(Bs + (r * 66 + xi) * 40 + ci8 * 8) = v;
    }
    __syncthreads();
#pragma unroll
    for (int sh = 0; sh < 9; ++sh) {
      int dyv = sh / 3, dxv = sh - dyv * 3;
      const short* wbase = wbP + ((sh * 4) * KS + ks) * 512 + lane * 8;
      bf16x8 a0 = *(const bf16x8*)(wbase);
      bf16x8 a1 = *(const bf16x8*)(wbase + KS * 512);
      bf16x8 a2 = *(const bf16x8*)(wbase + 2 * KS * 512);
      bf16x8 a3 = *(const bf16x8*)(wbase + 3 * KS * 512);
      int xi = w * 16 + l15 + dxv;
      bf16x8 bf = *(const bf16x8*)(Bs + (dyv * 66 + xi) * 40 + quad * 8);
      acc[0] = MFMA16(a0, bf, acc[0]);
      acc[1] = MFMA16(a1, bf, acc[1]);
      acc[2] = MFMA16(a2, bf, acc[2]);
      acc[3] = MFMA16(a3, bf, acc[3]);
    }
  }
  // epilogue: lrelu(conv + addn(frag-packed)), stores, optional rgb
  int x = xh * 64 + w * 16 + l15;
  long nidx = ((long)(b * 128 + y)) * 128 + x;
  long ntile = (long)b * 1024 + y * 8 + xh * 4 + w;
  float p0 = 0.f, p1 = 0.f, p2 = 0.f;
#pragma unroll
  for (int ct = 0; ct < 4; ++ct) {
    short4 ad = *(const short4*)(addnP + (ntile * 4 + ct) * 256 + lane * 4);
    float av[4] = {bf2f(ad.x), bf2f(ad.y), bf2f(ad.z), bf2f(ad.w)};
    float v[4];
#pragma unroll
    for (int r = 0; r < 4; ++r) {
      float a = acc[ct][r] + av[r];
      v[r] = a > 0.f ? a : 0.2f * a;
    }
    if (out_nchw) {
#pragma unroll
      for (int r = 0; r < 4; ++r) {
        int co = ct * 16 + quad * 4 + r;
        out_nchw[((long)(b * 64 + co)) * 16384 + y * 128 + x] = v[r];
      }
    }
    if (out_nhwc) {
      short4 pv;
      pv.x = f2bf(v[0]); pv.y = f2bf(v[1]); pv.z = f2bf(v[2]); pv.w = f2bf(v[3]);
      *(short4*)(out_nhwc + nidx * 64 + ct * 16 + quad * 4) = pv;
    }
    if (rgbw) {
#pragma unroll
      for (int r = 0; r < 4; ++r) {
        int co = ct * 16 + quad * 4 + r;
        float mv = (styleb[b * 64 + co] + 1.0f) * v[r];
        p0 += rgbw[co] * mv;
        p1 += rgbw[64 + co] * mv;
        p2 += rgbw[128 + co] * mv;
      }
    }
  }
  if (rgbw) {
    p0 += __shfl_xor(p0, 16); p0 += __shfl_xor(p0, 32);
    p1 += __shfl_xor(p1, 16); p1 += __shfl_xor(p1, 32);
    p2 += __shfl_xor(p2, 16); p2 += __shfl_xor(p2, 32);
    if (quad == 0) {
      long pi = y * 128 + x;
      rgbs[((long)(b * 3 + 0)) * 16384 + pi] = p0 + prev[((long)(b * 3 + 0)) * 16384 + pi];
      rgbs[((long)(b * 3 + 1)) * 16384 + pi] = p1 + prev[((long)(b * 3 + 1)) * 16384 + pi];
      rgbs[((long)(b * 3 + 2)) * 16384 + pi] = p2 + prev[((long)(b * 3 + 2)) * 16384 + pi];
    }
  }
}

// ---------------- fused bilinear up2 + [1,2,1] blur (rgb tail) ---------------------------
__global__ void upblur_kernel(const float* __restrict__ rgbs, float* __restrict__ out) {
  __shared__ float rows[3][128];
  int bc = blockIdx.y, Y = blockIdx.x, X = threadIdx.x;
  int m = Y >> 1;
  const float* base = rgbs + (long)bc * 16384;
  for (int t = X; t < 384; t += 256) {
    int sr = t >> 7, xx = t & 127;
    int rr = m - 1 + sr;
    rr = rr < 0 ? 0 : (rr > 127 ? 127 : rr);
    rows[sr][xx] = base[rr * 128 + xx];
  }
  __syncthreads();
  const float w3[3] = {1.f, 2.f, 1.f};
  float s = 0.f;
#pragma unroll
  for (int dy = -1; dy <= 1; ++dy) {
    int Yv = Y + dy;
    if (Yv < 0 || Yv > 255) continue;
    float iy = Yv * 0.5f - 0.25f;
    int y0 = (int)floorf(iy); float wy = iy - (float)y0;
    int ylo = y0 < 0 ? 0 : y0;
    int yhi = y0 + 1 > 127 ? 127 : y0 + 1;
    int slo = ylo - m + 1, shi = yhi - m + 1;
#pragma unroll
    for (int dx = -1; dx <= 1; ++dx) {
      int Xv = X + dx;
      if (Xv < 0 || Xv > 255) continue;
      float ix = Xv * 0.5f - 0.25f;
      int x0 = (int)floorf(ix); float wx = ix - (float)x0;
      int xlo = x0 < 0 ? 0 : x0;
      int xhi = x0 + 1 > 127 ? 127 : x0 + 1;
      float v = (1.f - wy) * ((1.f - wx) * rows[slo][xlo] + wx * rows[slo][xhi])
              + wy * ((1.f - wx) * rows[shi][xlo] + wx * rows[shi][xhi]);
      s += w3[dy + 1] * w3[dx + 1] * v;
    }
  }
  out[(long)bc * 65536 + Y * 256 + X] = s * (1.0f / 16.0f);
}

extern "C" void kernel_launch(void* const* d_in, const int* in_sizes, int n_in,
                              void* d_out, int out_size, void* d_ws, size_t ws_size,
                              hipStream_t stream) {
  (void)in_sizes; (void)n_in; (void)out_size; (void)ws_size;
  const float* x        = (const float*)d_in[0];
  const float* prev_rgb = (const float*)d_in[1];
  const float* istyle   = (const float*)d_in[2];
  const float* noise1   = (const float*)d_in[3];
  const float* noise2   = (const float*)d_in[4];
  const float* conv1_w  = (const float*)d_in[5];
  const float* conv2_w  = (const float*)d_in[6];
  const float* style_w  = (const float*)d_in[7];
  const float* style_b  = (const float*)d_in[8];
  const float* rgb_w    = (const float*)d_in[9];
  const float* qw       = (const float*)d_in[10];
  const float* kw       = (const float*)d_in[11];
  const float* vw       = (const float*)d_in[12];
  const float* ow       = (const float*)d_in[13];
  const float* ob       = (const float*)d_in[14];
  const float* ga       = (const float*)d_in[15];
  const float* f1w      = (const float*)d_in[16];
  const float* f1b      = (const float*)d_in[17];
  const float* f2w      = (const float*)d_in[18];
  const float* f2b      = (const float*)d_in[19];
  const float* gf       = (const float*)d_in[20];
  float* out_x   = (float*)d_out;
  float* out_rgb = out_x + 4194304;
  float* ws = (float*)d_ws;

  short* xupT   = (short*)(ws + OFF_XUPT);
  short* xaT    = (short*)(ws + OFF_XAT);
  short* nbufP  = (short*)(ws + OFF_NBT);
  short* nzP    = (short*)(ws + OFF_NZT);
  short* Gpartb = (short*)(ws + OFF_GPART);
  short* wb1    = (short*)(ws + OFF_WB1);
  short* wb2    = (short*)(ws + OFF_WB2);
  float* styleb = ws + OFF_STYLE;
  float* rgbs   = ws + OFF_RGBS;
  short* qwP    = (short*)(ws + OFF_QWB);
  short* kwP    = (short*)(ws + OFF_KWB);
  short* f1P    = (short*)(ws + OFF_F1WB);
  short* f2P    = (short*)(ws + OFF_F2WB);
  short* MtP    = (short*)(ws + OFF_MTT);
  float* Gsum   = ws + OFF_GSUM;

  // fused prep: cvt4+style | wnorm2 | up2t (all independent, one launch)
  prep_kernel<<<1025, 256, 0, stream>>>(qw, kw, f1w, f2w, qwP, kwP, f1P, f2P,
                                        istyle, style_w, style_b, styleb,
                                        conv1_w, conv2_w, wb1, wb2, x, xupT);

  // attention path (pk also packs nzP)
  pk_kernel<<<dim3(8, 128), 256, 0, stream>>>(noise1, noise2, nzP, kwP, Gpartb);
  gsum_kernel<<<160, 256, 0, stream>>>(Gpartb, Gsum);
  ctxM_kernel<<<dim3(16, NB, 2), 256, 0, stream>>>(Gsum, vw, ow, MtP);
  attnd4_kernel<<<dim3(8, 256), 256, 0, stream>>>(nzP, qwP, MtP, ob, ga,
                                                  f1P, f1b, f2P, f2b, gf, nbufP);

  // conv chain (dependent, stays serial)
  convmfma_kernel<<<dim3(2, 128, NB), 256, 0, stream>>>(
      xupT, 128, wb1, nbufP, nullptr, xaT, nullptr, nullptr, nullptr, nullptr);
  convmfma_kernel<<<dim3(2, 128, NB), 256, 0, stream>>>(
      xaT, 64, wb2, nbufP + 4194304L, out_x, nullptr, rgb_w, styleb, prev_rgb, rgbs);

  upblur_kernel<<<dim3(256, 12), 256, 0, stream>>>(rgbs, out_rgb);
}

// Round 13
// 267.589 us; speedup vs baseline: 1.1139x; 1.0065x over previous
//
#include <hip/hip_runtime.h>
#include <math.h>

#define NB 4
#define NF 64
#define NPIX 16384
#define DK 256
#define DV 512
#define QKSCALE 0.4204482f

typedef __attribute__((ext_vector_type(8))) short bf16x8;
typedef __attribute__((ext_vector_type(4))) float f32x4;
#define MFMA16(a, b, c) __builtin_amdgcn_mfma_f32_16x16x32_bf16(a, b, c, 0, 0, 0)

// hardware bf16 convert (v_cvt_pk_bf16_f32, RNE) -- bit-identical to software RNE.
__device__ __forceinline__ short f2bf(float f) {
  __bf16 h = (__bf16)f;
  return __builtin_bit_cast(short, h);
}
__device__ __forceinline__ float bf2f(short s) {
  unsigned u = ((unsigned)(unsigned short)s) << 16;
  return __builtin_bit_cast(float, u);
}

// workspace offsets (float units)
#define OFF_XUPT   0L          // bf16 [4][128y][128x][128c]  4,194,304 f
#define OFF_XAT    4194304L    // bf16 [4][128y][128x][64c]   2,097,152 f
#define OFF_NBT    6291456L    // bf16 frag-packed [8bi][1024nt][4ct][64lane][4]  4,194,304 f
#define OFF_NZT    10485760L   // bf16 frag-packed [8bi][1024nt][2ks][64lane][8]  4,194,304 f
#define OFF_GPART  14680064L   // bf16 [8bi][128ch][256][80] 10,485,760 f
#define OFF_WB1    25165824L   // bf16 frag-packed [9sh][4ct][4ks][512]  36,864 f
#define OFF_WB2    25202688L   // bf16 frag-packed [9sh][4ct][2ks][512]  18,432 f
#define OFF_STYLE  25221120L   // [4][64] fp32                      256
#define OFF_RGBS   25221376L   // [4][3][128][128] fp32         196,608
#define OFF_QWB    25417984L   // bf16 frag-packed [2][16hd][2ks][512]   16,384 f
#define OFF_KWB    25434368L   // bf16 frag-packed [2][4q][4dt][2ks][512] 16,384 f
#define OFF_F1WB   25450752L   // bf16 frag-packed [2][8jt][2ks][512]     8,192 f
#define OFF_F2WB   25458944L   // bf16 frag-packed [2][4ct][2p][2ks][512] 8,192 f
#define OFF_MTT    25467136L   // bf16 frag-packed [8bi][4ct][8h][512]   65,536 f
#define OFF_GSUM   25532672L   // fp32 [8bi][256][80]           163,840 f
// total 25,696,512 floats = 102.8 MB

#define CDIV(a,b) (((a)+(b)-1)/(b))

// ---------------- fused prep: cvt4+style (0..384), wnorm2 (385..512), up2t (513..1024) ---
__global__ __launch_bounds__(256) void prep_kernel(
    const float* __restrict__ qw, const float* __restrict__ kw,
    const float* __restrict__ f1w, const float* __restrict__ f2w,
    short* __restrict__ qwP, short* __restrict__ kwP,
    short* __restrict__ f1P, short* __restrict__ f2P,
    const float* __restrict__ istyle, const float* __restrict__ sw,
    const float* __restrict__ sb, float* __restrict__ styleb,
    const float* __restrict__ W1, const float* __restrict__ W2,
    short* __restrict__ wb1, short* __restrict__ wb2,
    const float* __restrict__ xin, short* __restrict__ xupT) {
  __shared__ float shmem[64 * 132];
  int bid = blockIdx.x;
  int tid = threadIdx.x;
  if (bid < 384) {   // cvt4: fp32 -> bf16 fragment-packed attn weights
    int i = bid * 256 + tid;   // 98304 total
    if (i < 32768) {
      int i_t = i >> 14, rem = i & 16383;
      int hd = rem >> 10, ks = (rem >> 9) & 1, lane = (rem >> 3) & 63, j = rem & 7;
      int l15 = lane & 15, quad = lane >> 4;
      qwP[i] = f2bf(qw[i_t * 16384 + (hd * 16 + l15) * 64 + ks * 32 + quad * 8 + j]);
    } else if (i < 65536) {
      int ii = i - 32768;
      int i_t = ii >> 14, rem = ii & 16383;
      int q = rem >> 12, dt = (rem >> 10) & 3, ks = (rem >> 9) & 1, lane = (rem >> 3) & 63, j = rem & 7;
      int l15 = lane & 15, quad = lane >> 4;
      kwP[ii] = f2bf(kw[i_t * 16384 + (q * 64 + dt * 16 + l15) * 64 + ks * 32 + quad * 8 + j]);
    } else if (i < 81920) {
      int ii = i - 65536;
      int i_t = ii >> 13, rem = ii & 8191;
      int jt = rem >> 10, ks = (rem >> 9) & 1, lane = (rem >> 3) & 63, j = rem & 7;
      int l15 = lane & 15, quad = lane >> 4;
      f1P[ii] = f2bf(f1w[i_t * 8192 + (jt * 16 + l15) * 64 + ks * 32 + quad * 8 + j]);
    } else {
      int ii = i - 81920;
      int i_t = ii >> 13, rem = ii & 8191;
      int ct = rem >> 11, p = (rem >> 10) & 1, ks = (rem >> 9) & 1, lane = (rem >> 3) & 63, j = rem & 7;
      int l15 = lane & 15, quad = lane >> 4;
      f2P[ii] = f2bf(f2w[i_t * 8192 + (ct * 16 + l15) * 128 + p * 64 + ks * 32 + quad * 8 + j]);
    }
    return;
  }
  if (bid == 384) {   // style
    int b = tid >> 6;
    int c = tid & 63;
    float a = 0.f;
    const float* ip = istyle + b * 512;
    const float* wp = sw + c * 512;
    for (int l = 0; l < 512; ++l) a += ip[l] * wp[l];
    styleb[b * 64 + c] = a + sb[c];
    return;
  }
  if (bid < 513) {   // wnorm: demod weight prep -> frag-packed
    int wb_ = bid - 385;
    int which = wb_ >> 6;
    int co = wb_ & 63;
    const float* W = which ? W2 : W1;
    short* wbP = which ? wb2 : wb1;
    int CI = which ? 64 : 128;
    int n = CI * 9;
    int KS = CI >> 5;
    float* red = shmem;
    float s = 0.f;
    for (int idx = tid; idx < n; idx += 256) {
      float w2 = 2.0f * W[co * n + idx];
      s += w2 * w2;
    }
    red[tid] = s;
    __syncthreads();
    for (int off = 128; off > 0; off >>= 1) {
      if (tid < off) red[tid] += red[tid + off];
      __syncthreads();
    }
    float sc = rsqrtf(red[0] + 1e-8f);
    int ct = co >> 4, l15 = co & 15;
    for (int idx = tid; idx < n; idx += 256) {
      int ci = idx / 9, k = idx - ci * 9;
      int ks = ci >> 5, quad = (ci >> 3) & 3, j = ci & 7;
      wbP[((k * 4 + ct) * KS + ks) * 512 + (quad * 16 + l15) * 8 + j] =
          f2bf(2.0f * W[co * n + idx] * sc);
    }
    return;
  }
  // up2t: fused bilinear up2 + NCHW->NHWC bf16, coalesced stores
  int idx0 = bid - 513;
  int b = idx0 >> 7, y = idx0 & 127;
  int w = tid >> 6, lane = tid & 63, quad = lane >> 4, l15 = lane & 15;
  float* row = shmem;   // [xin64][c pad132]
  float iy = y * 0.5f - 0.25f;
  int y0 = (int)floorf(iy); float wy = iy - (float)y0;
  int ylo = y0 < 0 ? 0 : y0;
  int yhi = y0 + 1 > 63 ? 63 : y0 + 1;
  for (int it = 0; it < 32; ++it) {
    int idx = it * 256 + tid;
    int c = idx >> 6, xi = idx & 63;
    const float* bp = xin + ((long)(b * 128 + c)) * 4096;
    float v0 = bp[ylo * 64 + xi];
    float v1 = bp[yhi * 64 + xi];
    row[xi * 132 + c] = (1.f - wy) * v0 + wy * v1;
  }
  __syncthreads();
  long ybase = (((long)(b * 128 + y)) * 128) * 128;
#pragma unroll
  for (int s = 0; s < 8; ++s) {
    int x = w * 32 + s * 4 + quad;
    float ix = x * 0.5f - 0.25f;
    int x0 = (int)floorf(ix); float wx = ix - (float)x0;
    int xlo = x0 < 0 ? 0 : x0;
    int xhi = x0 + 1 > 63 ? 63 : x0 + 1;
    bf16x8 pack;
#pragma unroll
    for (int j = 0; j < 8; ++j) {
      int c = l15 * 8 + j;
      float v = (1.f - wx) * row[xlo * 132 + c] + wx * row[xhi * 132 + c];
      pack[j] = f2bf(v);
    }
    *(bf16x8*)(xupT + ybase + (long)x * 128 + l15 * 8) = pack;
  }
}

// ---------------- pk: Gpart = exp(kw@X) @ [X^T | 1 | 0]; packs nzP; kw loads pipelined ---
// grid (8 bi, 128 ch). Each block stages X once (float4), emits the 16 nzP fragments
// for its 128-px chunk, and builds its own B-fragments from LDS. kwP fragments for
// iteration q+1 are issued during q's softmax/G phase (R12's attnd4 recipe).
__global__ __launch_bounds__(256, 4) void pk_kernel(const float* __restrict__ nz1,
                                                    const float* __restrict__ nz2,
                                                    short* __restrict__ nzP,
                                                    const short* __restrict__ kwP,
                                                    short* __restrict__ Gpartb) {
  __shared__ __attribute__((aligned(16))) char lds[39168];
  int bi = blockIdx.x, ch = blockIdx.y;
  int i = bi >> 2, b = bi & 3;
  const float* nz = (i == 0) ? nz1 : nz2;
  const short* kwP_i = kwP + i * (DK * NF);
  int tid = threadIdx.x;
  int w = tid >> 6, lane = tid & 63, quad = lane >> 4, l15 = lane & 15;
  int n0 = ch * 128;
  short* Xb = (short*)lds;               // [80][136]
  short* Ph = (short*)(lds + 21760);     // [64][136]
  // float4 staging: wave = 2 c-rows x 512B contiguous
#pragma unroll
  for (int k = 0; k < 8; ++k) {
    int idx = tid + k * 256;
    int c = idx >> 5, g = idx & 31;
    float4 v = *(const float4*)(nz + ((long)b * 64 + c) * NPIX + n0 + g * 4);
    short* xp = Xb + c * 136 + g * 4;
    xp[0] = f2bf(v.x); xp[1] = f2bf(v.y); xp[2] = f2bf(v.z); xp[3] = f2bf(v.w);
  }
  for (int k = 0; k < 8; ++k) {
    int idx = tid + k * 256;
    int c = 64 + (idx >> 7), n = idx & 127;
    Xb[c * 136 + n] = (c == 64) ? (short)0x3F80 : (short)0;
  }
  // preload q=0's kw fragments while staging drains
  bf16x8 kf[2][4];
#pragma unroll
  for (int ks = 0; ks < 2; ++ks)
#pragma unroll
    for (int dt = 0; dt < 4; ++dt)
      kf[ks][dt] = *(const bf16x8*)(kwP_i + ((dt * 2 + ks) * 512 + lane * 8));
  __syncthreads();
  // pack the 16 nzP fragments (8 ntiles x 2 ks) for this 128-px chunk: 1024 slots
  long fragb = (long)bi * 1024 + ch * 8;
#pragma unroll
  for (int v = 0; v < 4; ++v) {
    int slot = tid + v * 256;
    int frag = slot >> 6, ln = slot & 63;
    int nt = frag >> 1, ksf = frag & 1;
    int fl15 = ln & 15, fq = ln >> 4;
    bf16x8 pack;
#pragma unroll
    for (int j = 0; j < 8; ++j)
      pack[j] = Xb[(ksf * 32 + fq * 8 + j) * 136 + nt * 16 + fl15];
    *(bf16x8*)(nzP + ((fragb + nt) * 2 + ksf) * 512 + ln * 8) = pack;
  }
  // build this wave's B fragments from Xb
  bf16x8 bfr[2][2];
#pragma unroll
  for (int j = 0; j < 2; ++j)
#pragma unroll
    for (int ks = 0; ks < 2; ++ks)
#pragma unroll
      for (int jj = 0; jj < 8; ++jj)
        bfr[j][ks][jj] = Xb[(ks * 32 + quad * 8 + jj) * 136 + (2 * w + j) * 16 + l15];
  for (int q = 0; q < 4; ++q) {
    f32x4 acc[2][4];
#pragma unroll
    for (int j = 0; j < 2; ++j)
#pragma unroll
      for (int dt = 0; dt < 4; ++dt) acc[j][dt] = (f32x4){0.f, 0.f, 0.f, 0.f};
#pragma unroll
    for (int j = 0; j < 2; ++j)
#pragma unroll
      for (int ks = 0; ks < 2; ++ks)
#pragma unroll
        for (int dt = 0; dt < 4; ++dt)
          acc[j][dt] = MFMA16(kf[ks][dt], bfr[j][ks], acc[j][dt]);
    // prefetch next q's kw fragments -- latency hides under exp + Ph + barrier + G-GEMM
    if (q < 3) {
#pragma unroll
      for (int ks = 0; ks < 2; ++ks)
#pragma unroll
        for (int dt = 0; dt < 4; ++dt)
          kf[ks][dt] = *(const bf16x8*)(kwP_i +
              ((((q + 1) * 4 + dt) * 2 + ks) * 512 + lane * 8));
    }
#pragma unroll
    for (int j = 0; j < 2; ++j) {
      int ntile = 2 * w + j;
#pragma unroll
      for (int dt = 0; dt < 4; ++dt)
#pragma unroll
        for (int r = 0; r < 4; ++r) {
          float p = __expf(acc[j][dt][r] * QKSCALE);
          Ph[(dt * 16 + quad * 4 + r) * 136 + ntile * 16 + l15] = f2bf(p);
        }
    }
    __syncthreads();
#pragma unroll
    for (int ct = 0; ct < 5; ++ct) {
      f32x4 g = (f32x4){0.f, 0.f, 0.f, 0.f};
#pragma unroll
      for (int ks = 0; ks < 4; ++ks) {
        bf16x8 afr = *(const bf16x8*)(Ph + (w * 16 + l15) * 136 + ks * 32 + quad * 8);
        bf16x8 bfr2 = *(const bf16x8*)(Xb + (ct * 16 + l15) * 136 + ks * 32 + quad * 8);
        g = MFMA16(afr, bfr2, g);
      }
#pragma unroll
      for (int r = 0; r < 4; ++r) {
        int row = q * 64 + w * 16 + quad * 4 + r;
        Gpartb[(((long)bi * 128 + ch) * 256 + row) * 80 + ct * 16 + l15] = f2bf(g[r]);
      }
    }
    __syncthreads();
  }
}

// ---------------- gsum: reduce Gpart over ch -> Gsum fp32 [bi][256][80], short4/lane -----
__global__ __launch_bounds__(256) void gsum_kernel(const short* __restrict__ Gpartb,
                                                   float* __restrict__ Gsum) {
  int idx4 = blockIdx.x * 256 + threadIdx.x;   // 40960 total
  int bi = idx4 / 5120;
  int rem4 = idx4 - bi * 5120;
  const short* gp = Gpartb + (long)bi * 128 * 20480 + rem4 * 4;
  float a0 = 0.f, a1 = 0.f, a2 = 0.f, a3 = 0.f;
#pragma unroll 8
  for (int ch = 0; ch < 128; ++ch) {
    short4 v = *(const short4*)(gp + (long)ch * 20480);
    a0 += bf2f(v.x); a1 += bf2f(v.y); a2 += bf2f(v.z); a3 += bf2f(v.w);
  }
  float4 o = {a0, a1, a2, a3};
  *(float4*)(Gsum + (long)bi * 20480 + rem4 * 4) = o;
}

// ---------------- ctxM: Gsum -> ctx -> MtP (fragment-packed) -----------------------------
__global__ __launch_bounds__(256) void ctxM_kernel(const float* __restrict__ Gsum,
                                                   const float* __restrict__ vw,
                                                   const float* __restrict__ ow,
                                                   short* __restrict__ MtP) {
  int i = blockIdx.z, b = blockIdx.y, dt = blockIdx.x * 16;
  int h = dt >> 5;
  __shared__ float Gs[16][81];
  __shared__ float ctxs[16][68];
  int t = threadIdx.x;
  const float* gsb = Gsum + ((long)(i * NB + b)) * 20480;
  for (int idx = t; idx < 1280; idx += 256) {
    int dl = idx / 80, c = idx - dl * 80;
    Gs[dl][c] = gsb[(dt + dl) * 80 + c];
  }
  __syncthreads();
  const float* vw_i = vw + (long)i * DV * NF;
  const float* ow_i = ow + (long)i * NF * DV;
  for (int idx = t; idx < 1024; idx += 256) {
    int dl = idx & 15, e = idx >> 4;
    const float* vp = vw_i + (h * 64 + e) * 64;
    float a = 0.f;
#pragma unroll
    for (int c = 0; c < 64; ++c) a += Gs[dl][c] * vp[c];
    ctxs[dl][e] = a / Gs[dl][64];
  }
  __syncthreads();
  // MtP[bi][ct4][h8][lane][8] = MtT[c=ct*16+l15][d=h*32+quad*8+r]
  short* mtp = MtP + ((long)(i * NB + b)) * 16384;
  for (int idx = t; idx < 1024; idx += 256) {
    int dl = idx & 15, c = idx >> 4;
    const float* op = ow_i + c * 512 + h * 64;
    float a = 0.f;
#pragma unroll
    for (int e = 0; e < 64; ++e) a += op[e] * ctxs[dl][e];
    int d = dt + dl;
    int ct = c >> 4, l15 = c & 15, hh = d >> 5, quad = (d >> 3) & 3, r = d & 7;
    mtp[((ct * 8 + hh) * 64 + quad * 16 + l15) * 8 + r] = f2bf(a);
  }
}

// ---------------- attnd4: fused attn+FF, software-pipelined A-fragment loads -------------
// grid (8 bi, 256 x), block 256 = 4 waves, 16 px/wave. Per-wave LDS 4096 B.
__global__ __launch_bounds__(256, 5) void attnd4_kernel(
    const short* __restrict__ nzP, const short* __restrict__ qwP,
    const short* __restrict__ MtP, const float* __restrict__ ob,
    const float* __restrict__ gap, const short* __restrict__ f1P,
    const float* __restrict__ f1b, const short* __restrict__ f2P,
    const float* __restrict__ f2b, const float* __restrict__ gfp,
    short* __restrict__ noutP) {
  __shared__ __attribute__((aligned(16))) short lds[4 * 2048];
  int bi = blockIdx.x;
  int i = bi >> 2;
  int tid = threadIdx.x;
  int w = tid >> 6, lane = tid & 63, quad = lane >> 4, l15 = lane & 15;
  short* Xt = lds + w * 2048;     // [16][72]
  short* Es = Xt + 1152;          // [16][56]
  float ga = gap[i], gf = gfp[i];
  const short* qwP_i = qwP + i * (DK * NF);
  const short* f1P_i = f1P + i * (128 * 64);
  const float* f1b_i = f1b + i * 128;
  const short* f2P_i = f2P + i * (64 * 128);
  const float* f2b_i = f2b + i * 64;
  const float* ob_i = ob + i * 64;
  long ntile = (long)bi * 1024 + blockIdx.y * 4 + w;
  // stage X: two fully-coalesced 1KB fragment loads, mirror into LDS for residual
  const short* nb = nzP + ntile * 1024;
  bf16x8 xfr0 = *(const bf16x8*)(nb + lane * 8);
  bf16x8 xfr1 = *(const bf16x8*)(nb + 512 + lane * 8);
  *(bf16x8*)(Xt + l15 * 72 + quad * 8) = xfr0;
  *(bf16x8*)(Xt + l15 * 72 + 32 + quad * 8) = xfr1;
  const short* mtp = MtP + (long)bi * 16384;
  f32x4 acc2[4];
#pragma unroll
  for (int ct = 0; ct < 4; ++ct) acc2[ct] = (f32x4){0.f, 0.f, 0.f, 0.f};
  // preload head 0's qw fragments
  bf16x8 qa00 = *(const bf16x8*)(qwP_i + 0 * 512 + lane * 8);
  bf16x8 qa01 = *(const bf16x8*)(qwP_i + 1 * 512 + lane * 8);
  bf16x8 qa10 = *(const bf16x8*)(qwP_i + 2 * 512 + lane * 8);
  bf16x8 qa11 = *(const bf16x8*)(qwP_i + 3 * 512 + lane * 8);
  // per-head: GEMM1 (q) -> softmax -> E-strip -> GEMM2 chunk; A-loads pipelined
#pragma unroll
  for (int h = 0; h < 8; ++h) {
    // issue this head's mtp fragment loads NOW (latency hides under softmax)
    bf16x8 m0 = *(const bf16x8*)(mtp + (0 * 8 + h) * 512 + lane * 8);
    bf16x8 m1 = *(const bf16x8*)(mtp + (1 * 8 + h) * 512 + lane * 8);
    bf16x8 m2 = *(const bf16x8*)(mtp + (2 * 8 + h) * 512 + lane * 8);
    bf16x8 m3 = *(const bf16x8*)(mtp + (3 * 8 + h) * 512 + lane * 8);
    f32x4 q[2];
    q[0] = (f32x4){0.f, 0.f, 0.f, 0.f};
    q[0] = MFMA16(qa00, xfr0, q[0]);
    q[0] = MFMA16(qa01, xfr1, q[0]);
    q[1] = (f32x4){0.f, 0.f, 0.f, 0.f};
    q[1] = MFMA16(qa10, xfr0, q[1]);
    q[1] = MFMA16(qa11, xfr1, q[1]);
    // prefetch next head's qw fragments (in flight during softmax + GEMM2)
    if (h < 7) {
      int hn = 2 * (h + 1);
      qa00 = *(const bf16x8*)(qwP_i + (hn * 2 + 0) * 512 + lane * 8);
      qa01 = *(const bf16x8*)(qwP_i + (hn * 2 + 1) * 512 + lane * 8);
      qa10 = *(const bf16x8*)(qwP_i + ((hn + 1) * 2 + 0) * 512 + lane * 8);
      qa11 = *(const bf16x8*)(qwP_i + ((hn + 1) * 2 + 1) * 512 + lane * 8);
    }
    float part = 0.f;
#pragma unroll
    for (int dd = 0; dd < 2; ++dd)
#pragma unroll
      for (int r = 0; r < 4; ++r) {
        float e = __expf(q[dd][r] * QKSCALE);
        q[dd][r] = e;
        part += e;
      }
    float p2 = part + __shfl_xor(part, 16);
    float s = p2 + __shfl_xor(p2, 32);
    float inv = 1.0f / s;
#pragma unroll
    for (int dd = 0; dd < 2; ++dd) {
      short4 ev;
      ev.x = f2bf(q[dd][0] * inv); ev.y = f2bf(q[dd][1] * inv);
      ev.z = f2bf(q[dd][2] * inv); ev.w = f2bf(q[dd][3] * inv);
      *(short4*)(Es + l15 * 56 + dd * 16 + quad * 4) = ev;
    }
    bf16x8 efr = *(const bf16x8*)(Es + l15 * 56 + quad * 8);
    acc2[0] = MFMA16(m0, efr, acc2[0]);
    acc2[1] = MFMA16(m1, efr, acc2[1]);
    acc2[2] = MFMA16(m2, efr, acc2[2]);
    acc2[3] = MFMA16(m3, efr, acc2[3]);
  }
  // residual y = x + ga*(o + ob): x from LDS bf16, y back to Xt + fp32 regs
  float yreg[4][4];
#pragma unroll
  for (int ct = 0; ct < 4; ++ct) {
    int c0 = ct * 16 + quad * 4;
    short4 xs = *(const short4*)(Xt + l15 * 72 + c0);
    float xv[4] = {bf2f(xs.x), bf2f(xs.y), bf2f(xs.z), bf2f(xs.w)};
    short4 ys;
#pragma unroll
    for (int r = 0; r < 4; ++r) yreg[ct][r] = xv[r] + ga * (acc2[ct][r] + ob_i[c0 + r]);
    ys.x = f2bf(yreg[ct][0]); ys.y = f2bf(yreg[ct][1]);
    ys.z = f2bf(yreg[ct][2]); ys.w = f2bf(yreg[ct][3]);
    *(short4*)(Xt + l15 * 72 + c0) = ys;
  }
  bf16x8 yfr0 = *(const bf16x8*)(Xt + l15 * 72 + quad * 8);
  bf16x8 yfr1 = *(const bf16x8*)(Xt + l15 * 72 + 32 + quad * 8);
  // GEMM3: h1[128j x 16n]
  f32x4 acc3[8];
#pragma unroll
  for (int jt = 0; jt < 8; ++jt) {
    acc3[jt] = (f32x4){0.f, 0.f, 0.f, 0.f};
    bf16x8 a0 = *(const bf16x8*)(f1P_i + (jt * 2 + 0) * 512 + lane * 8);
    acc3[jt] = MFMA16(a0, yfr0, acc3[jt]);
    bf16x8 a1 = *(const bf16x8*)(f1P_i + (jt * 2 + 1) * 512 + lane * 8);
    acc3[jt] = MFMA16(a1, yfr1, acc3[jt]);
  }
  // GEMM4 in 2 chunks of 64 j through the Xt strip
  f32x4 acc4[4];
#pragma unroll
  for (int ct = 0; ct < 4; ++ct) acc4[ct] = (f32x4){0.f, 0.f, 0.f, 0.f};
#pragma unroll
  for (int p = 0; p < 2; ++p) {
#pragma unroll
    for (int jj = 0; jj < 4; ++jj) {
      int jt = p * 4 + jj;
      short4 hs;
#pragma unroll
      for (int r = 0; r < 4; ++r) {
        float a = acc3[jt][r] + f1b_i[jt * 16 + quad * 4 + r];
        a = a > 0.f ? a : 0.2f * a;
        ((short*)&hs)[r] = f2bf(a);
      }
      *(short4*)(Xt + l15 * 72 + jj * 16 + quad * 4) = hs;
    }
    bf16x8 h0 = *(const bf16x8*)(Xt + l15 * 72 + quad * 8);
    bf16x8 h1 = *(const bf16x8*)(Xt + l15 * 72 + 32 + quad * 8);
#pragma unroll
    for (int ct = 0; ct < 4; ++ct) {
      bf16x8 a0 = *(const bf16x8*)(f2P_i + ((ct * 2 + p) * 2 + 0) * 512 + lane * 8);
      acc4[ct] = MFMA16(a0, h0, acc4[ct]);
      bf16x8 a1 = *(const bf16x8*)(f2P_i + ((ct * 2 + p) * 2 + 1) * 512 + lane * 8);
      acc4[ct] = MFMA16(a1, h1, acc4[ct]);
    }
  }
  // output fragment-packed: noutP[ntile][ct][lane][4] -- 512B coalesced per store
#pragma unroll
  for (int ct = 0; ct < 4; ++ct) {
    int c0 = ct * 16 + quad * 4;
    short4 ov;
#pragma unroll
    for (int r = 0; r < 4; ++r)
      ((short*)&ov)[r] = f2bf(yreg[ct][r] + gf * (acc4[ct][r] + f2b_i[c0 + r]));
    *(short4*)(noutP + (ntile * 4 + ct) * 256 + lane * 4) = ov;
  }
}

// ---------------- MFMA 3x3 conv: NHWC bf16 in, frag-packed weights+addend, lrelu, +rgb ---
// grid (2 xh, 128 y, NB). wave w -> one 16-px ntile; block covers 64 px (half row).
__global__ __launch_bounds__(256, 4) void convmfma_kernel(
    const short* __restrict__ inT, int CI, const short* __restrict__ wbP,
    const short* __restrict__ addnP, float* __restrict__ out_nchw,
    short* __restrict__ out_nhwc, const float* __restrict__ rgbw,
    const float* __restrict__ styleb, const float* __restrict__ prev,
    float* __restrict__ rgbs) {
  __shared__ __attribute__((aligned(16))) short Bs[3 * 66 * 40];  // [r][xi][ci32 pad40]
  int xh = blockIdx.x, y = blockIdx.y, b = blockIdx.z;
  int tid = threadIdx.x;
  int w = tid >> 6, lane = tid & 63, quad = lane >> 4, l15 = lane & 15;
  int KS = CI >> 5;
  f32x4 acc[4];
#pragma unroll
  for (int ct = 0; ct < 4; ++ct) acc[ct] = (f32x4){0.f, 0.f, 0.f, 0.f};
  for (int ks = 0; ks < KS; ++ks) {
    if (ks) __syncthreads();
    for (int t = tid; t < 792; t += 256) {
      int ci8 = t & 3, xr = t >> 2;
      int xi = xr % 66, r = xr / 66;
      int gy = y + r - 1, gx = xh * 64 + xi - 1;
      bf16x8 v = {0, 0, 0, 0, 0, 0, 0, 0};
      if (gy >= 0 && gy < 128 && gx >= 0 && gx < 128)
        v = *(const bf16x8*)(inT + (((long)(b * 128 + gy)) * 128 + gx) * CI + ks * 32 + ci8 * 8);
      *(bf16x8*)(Bs + (r * 66 + xi) * 40 + ci8 * 8) = v;
    }
    __syncthreads();
#pragma unroll
    for (int sh = 0; sh < 9; ++sh) {
      int dyv = sh / 3, dxv = sh - dyv * 3;
      const short* wbase = wbP + ((sh * 4) * KS + ks) * 512 + lane * 8;
      bf16x8 a0 = *(const bf16x8*)(wbase);
      bf16x8 a1 = *(const bf16x8*)(wbase + KS * 512);
      bf16x8 a2 = *(const bf16x8*)(wbase + 2 * KS * 512);
      bf16x8 a3 = *(const bf16x8*)(wbase + 3 * KS * 512);
      int xi = w * 16 + l15 + dxv;
      bf16x8 bf = *(const bf16x8*)(Bs + (dyv * 66 + xi) * 40 + quad * 8);
      acc[0] = MFMA16(a0, bf, acc[0]);
      acc[1] = MFMA16(a1, bf, acc[1]);
      acc[2] = MFMA16(a2, bf, acc[2]);
      acc[3] = MFMA16(a3, bf, acc[3]);
    }
  }
  // epilogue: lrelu(conv + addn(frag-packed)), stores, optional rgb
  int x = xh * 64 + w * 16 + l15;
  long nidx = ((long)(b * 128 + y)) * 128 + x;
  long ntile = (long)b * 1024 + y * 8 + xh * 4 + w;
  float p0 = 0.f, p1 = 0.f, p2 = 0.f;
#pragma unroll
  for (int ct = 0; ct < 4; ++ct) {
    short4 ad = *(const short4*)(addnP + (ntile * 4 + ct) * 256 + lane * 4);
    float av[4] = {bf2f(ad.x), bf2f(ad.y), bf2f(ad.z), bf2f(ad.w)};
    float v[4];
#pragma unroll
    for (int r = 0; r < 4; ++r) {
      float a = acc[ct][r] + av[r];
      v[r] = a > 0.f ? a : 0.2f * a;
    }
    if (out_nchw) {
#pragma unroll
      for (int r = 0; r < 4; ++r) {
        int co = ct * 16 + quad * 4 + r;
        out_nchw[((long)(b * 64 + co)) * 16384 + y * 128 + x] = v[r];
      }
    }
    if (out_nhwc) {
      short4 pv;
      pv.x = f2bf(v[0]); pv.y = f2bf(v[1]); pv.z = f2bf(v[2]); pv.w = f2bf(v[3]);
      *(short4*)(out_nhwc + nidx * 64 + ct * 16 + quad * 4) = pv;
    }
    if (rgbw) {
#pragma unroll
      for (int r = 0; r < 4; ++r) {
        int co = ct * 16 + quad * 4 + r;
        float mv = (styleb[b * 64 + co] + 1.0f) * v[r];
        p0 += rgbw[co] * mv;
        p1 += rgbw[64 + co] * mv;
        p2 += rgbw[128 + co] * mv;
      }
    }
  }
  if (rgbw) {
    p0 += __shfl_xor(p0, 16); p0 += __shfl_xor(p0, 32);
    p1 += __shfl_xor(p1, 16); p1 += __shfl_xor(p1, 32);
    p2 += __shfl_xor(p2, 16); p2 += __shfl_xor(p2, 32);
    if (quad == 0) {
      long pi = y * 128 + x;
      rgbs[((long)(b * 3 + 0)) * 16384 + pi] = p0 + prev[((long)(b * 3 + 0)) * 16384 + pi];
      rgbs[((long)(b * 3 + 1)) * 16384 + pi] = p1 + prev[((long)(b * 3 + 1)) * 16384 + pi];
      rgbs[((long)(b * 3 + 2)) * 16384 + pi] = p2 + prev[((long)(b * 3 + 2)) * 16384 + pi];
    }
  }
}

// ---------------- fused bilinear up2 + [1,2,1] blur (rgb tail) ---------------------------
__global__ void upblur_kernel(const float* __restrict__ rgbs, float* __restrict__ out) {
  __shared__ float rows[3][128];
  int bc = blockIdx.y, Y = blockIdx.x, X = threadIdx.x;
  int m = Y >> 1;
  const float* base = rgbs + (long)bc * 16384;
  for (int t = X; t < 384; t += 256) {
    int sr = t >> 7, xx = t & 127;
    int rr = m - 1 + sr;
    rr = rr < 0 ? 0 : (rr > 127 ? 127 : rr);
    rows[sr][xx] = base[rr * 128 + xx];
  }
  __syncthreads();
  const float w3[3] = {1.f, 2.f, 1.f};
  float s = 0.f;
#pragma unroll
  for (int dy = -1; dy <= 1; ++dy) {
    int Yv = Y + dy;
    if (Yv < 0 || Yv > 255) continue;
    float iy = Yv * 0.5f - 0.25f;
    int y0 = (int)floorf(iy); float wy = iy - (float)y0;
    int ylo = y0 < 0 ? 0 : y0;
    int yhi = y0 + 1 > 127 ? 127 : y0 + 1;
    int slo = ylo - m + 1, shi = yhi - m + 1;
#pragma unroll
    for (int dx = -1; dx <= 1; ++dx) {
      int Xv = X + dx;
      if (Xv < 0 || Xv > 255) continue;
      float ix = Xv * 0.5f - 0.25f;
      int x0 = (int)floorf(ix); float wx = ix - (float)x0;
      int xlo = x0 < 0 ? 0 : x0;
      int xhi = x0 + 1 > 127 ? 127 : x0 + 1;
      float v = (1.f - wy) * ((1.f - wx) * rows[slo][xlo] + wx * rows[slo][xhi])
              + wy * ((1.f - wx) * rows[shi][xlo] + wx * rows[shi][xhi]);
      s += w3[dy + 1] * w3[dx + 1] * v;
    }
  }
  out[(long)bc * 65536 + Y * 256 + X] = s * (1.0f / 16.0f);
}

extern "C" void kernel_launch(void* const* d_in, const int* in_sizes, int n_in,
                              void* d_out, int out_size, void* d_ws, size_t ws_size,
                              hipStream_t stream) {
  (void)in_sizes; (void)n_in; (void)out_size; (void)ws_size;
  const float* x        = (const float*)d_in[0];
  const float* prev_rgb = (const float*)d_in[1];
  const float* istyle   = (const float*)d_in[2];
  const float* noise1   = (const float*)d_in[3];
  const float* noise2   = (const float*)d_in[4];
  const float* conv1_w  = (const float*)d_in[5];
  const float* conv2_w  = (const float*)d_in[6];
  const float* style_w  = (const float*)d_in[7];
  const float* style_b  = (const float*)d_in[8];
  const float* rgb_w    = (const float*)d_in[9];
  const float* qw       = (const float*)d_in[10];
  const float* kw       = (const float*)d_in[11];
  const float* vw       = (const float*)d_in[12];
  const float* ow       = (const float*)d_in[13];
  const float* ob       = (const float*)d_in[14];
  const float* ga       = (const float*)d_in[15];
  const float* f1w      = (const float*)d_in[16];
  const float* f1b      = (const float*)d_in[17];
  const float* f2w      = (const float*)d_in[18];
  const float* f2b      = (const float*)d_in[19];
  const float* gf       = (const float*)d_in[20];
  float* out_x   = (float*)d_out;
  float* out_rgb = out_x + 4194304;
  float* ws = (float*)d_ws;

  short* xupT   = (short*)(ws + OFF_XUPT);
  short* xaT    = (short*)(ws + OFF_XAT);
  short* nbufP  = (short*)(ws + OFF_NBT);
  short* nzP    = (short*)(ws + OFF_NZT);
  short* Gpartb = (short*)(ws + OFF_GPART);
  short* wb1    = (short*)(ws + OFF_WB1);
  short* wb2    = (short*)(ws + OFF_WB2);
  float* styleb = ws + OFF_STYLE;
  float* rgbs   = ws + OFF_RGBS;
  short* qwP    = (short*)(ws + OFF_QWB);
  short* kwP    = (short*)(ws + OFF_KWB);
  short* f1P    = (short*)(ws + OFF_F1WB);
  short* f2P    = (short*)(ws + OFF_F2WB);
  short* MtP    = (short*)(ws + OFF_MTT);
  float* Gsum   = ws + OFF_GSUM;

  // fused prep: cvt4+style | wnorm2 | up2t (all independent, one launch)
  prep_kernel<<<1025, 256, 0, stream>>>(qw, kw, f1w, f2w, qwP, kwP, f1P, f2P,
                                        istyle, style_w, style_b, styleb,
                                        conv1_w, conv2_w, wb1, wb2, x, xupT);

  // attention path (pk also packs nzP)
  pk_kernel<<<dim3(8, 128), 256, 0, stream>>>(noise1, noise2, nzP, kwP, Gpartb);
  gsum_kernel<<<160, 256, 0, stream>>>(Gpartb, Gsum);
  ctxM_kernel<<<dim3(16, NB, 2), 256, 0, stream>>>(Gsum, vw, ow, MtP);
  attnd4_kernel<<<dim3(8, 256), 256, 0, stream>>>(nzP, qwP, MtP, ob, ga,
                                                  f1P, f1b, f2P, f2b, gf, nbufP);

  // conv chain (dependent, stays serial)
  convmfma_kernel<<<dim3(2, 128, NB), 256, 0, stream>>>(
      xupT, 128, wb1, nbufP, nullptr, xaT, nullptr, nullptr, nullptr, nullptr);
  convmfma_kernel<<<dim3(2, 128, NB), 256, 0, stream>>>(
      xaT, 64, wb2, nbufP + 4194304L, out_x, nullptr, rgb_w, styleb, prev_rgb, rgbs);

  upblur_kernel<<<dim3(256, 12), 256, 0, stream>>>(rgbs, out_rgb);
}

// Round 14
// 266.259 us; speedup vs baseline: 1.1194x; 1.0050x over previous
//
#include <hip/hip_runtime.h>
#include <math.h>

#define NB 4
#define NF 64
#define NPIX 16384
#define DK 256
#define DV 512
#define QKSCALE 0.4204482f

typedef __attribute__((ext_vector_type(8))) short bf16x8;
typedef __attribute__((ext_vector_type(4))) float f32x4;
#define MFMA16(a, b, c) __builtin_amdgcn_mfma_f32_16x16x32_bf16(a, b, c, 0, 0, 0)

// hardware bf16 convert (v_cvt_pk_bf16_f32, RNE) -- bit-identical to software RNE.
__device__ __forceinline__ short f2bf(float f) {
  __bf16 h = (__bf16)f;
  return __builtin_bit_cast(short, h);
}
__device__ __forceinline__ float bf2f(short s) {
  unsigned u = ((unsigned)(unsigned short)s) << 16;
  return __builtin_bit_cast(float, u);
}

// workspace offsets (float units)
#define OFF_XUPT   0L          // bf16 [4][128y][128x][128c]  4,194,304 f
#define OFF_XAT    4194304L    // bf16 [4][128y][128x][64c]   2,097,152 f
#define OFF_NBT    6291456L    // bf16 frag-packed [8bi][1024nt][4ct][64lane][4]  4,194,304 f
#define OFF_NZT    10485760L   // bf16 frag-packed [8bi][1024nt][2ks][64lane][8]  4,194,304 f
#define OFF_GPART  14680064L   // bf16 [8bi][128ch][256][80] 10,485,760 f
#define OFF_WB1    25165824L   // bf16 frag-packed [9sh][4ct][4ks][512]  36,864 f
#define OFF_WB2    25202688L   // bf16 frag-packed [9sh][4ct][2ks][512]  18,432 f
#define OFF_STYLE  25221120L   // [4][64] fp32                      256
#define OFF_RGBS   25221376L   // [4][3][128][128] fp32         196,608
#define OFF_QWB    25417984L   // bf16 frag-packed [2][16hd][2ks][512]   16,384 f
#define OFF_KWB    25434368L   // bf16 frag-packed [2][4q][4dt][2ks][512] 16,384 f
#define OFF_F1WB   25450752L   // bf16 frag-packed [2][8jt][2ks][512]     8,192 f
#define OFF_F2WB   25458944L   // bf16 frag-packed [2][4ct][2p][2ks][512] 8,192 f
#define OFF_MTT    25467136L   // bf16 frag-packed [8bi][4ct][8h][512]   65,536 f
#define OFF_GSUM   25532672L   // fp32 [8bi][256][80]           163,840 f
// total 25,696,512 floats = 102.8 MB

#define CDIV(a,b) (((a)+(b)-1)/(b))

// ---------------- fused prep: cvt4+style (0..384), wnorm2 (385..512), up2t (513..1024) ---
__global__ __launch_bounds__(256) void prep_kernel(
    const float* __restrict__ qw, const float* __restrict__ kw,
    const float* __restrict__ f1w, const float* __restrict__ f2w,
    short* __restrict__ qwP, short* __restrict__ kwP,
    short* __restrict__ f1P, short* __restrict__ f2P,
    const float* __restrict__ istyle, const float* __restrict__ sw,
    const float* __restrict__ sb, float* __restrict__ styleb,
    const float* __restrict__ W1, const float* __restrict__ W2,
    short* __restrict__ wb1, short* __restrict__ wb2,
    const float* __restrict__ xin, short* __restrict__ xupT) {
  __shared__ float shmem[64 * 132];
  int bid = blockIdx.x;
  int tid = threadIdx.x;
  if (bid < 384) {   // cvt4: fp32 -> bf16 fragment-packed attn weights
    int i = bid * 256 + tid;   // 98304 total
    if (i < 32768) {
      int i_t = i >> 14, rem = i & 16383;
      int hd = rem >> 10, ks = (rem >> 9) & 1, lane = (rem >> 3) & 63, j = rem & 7;
      int l15 = lane & 15, quad = lane >> 4;
      qwP[i] = f2bf(qw[i_t * 16384 + (hd * 16 + l15) * 64 + ks * 32 + quad * 8 + j]);
    } else if (i < 65536) {
      int ii = i - 32768;
      int i_t = ii >> 14, rem = ii & 16383;
      int q = rem >> 12, dt = (rem >> 10) & 3, ks = (rem >> 9) & 1, lane = (rem >> 3) & 63, j = rem & 7;
      int l15 = lane & 15, quad = lane >> 4;
      kwP[ii] = f2bf(kw[i_t * 16384 + (q * 64 + dt * 16 + l15) * 64 + ks * 32 + quad * 8 + j]);
    } else if (i < 81920) {
      int ii = i - 65536;
      int i_t = ii >> 13, rem = ii & 8191;
      int jt = rem >> 10, ks = (rem >> 9) & 1, lane = (rem >> 3) & 63, j = rem & 7;
      int l15 = lane & 15, quad = lane >> 4;
      f1P[ii] = f2bf(f1w[i_t * 8192 + (jt * 16 + l15) * 64 + ks * 32 + quad * 8 + j]);
    } else {
      int ii = i - 81920;
      int i_t = ii >> 13, rem = ii & 8191;
      int ct = rem >> 11, p = (rem >> 10) & 1, ks = (rem >> 9) & 1, lane = (rem >> 3) & 63, j = rem & 7;
      int l15 = lane & 15, quad = lane >> 4;
      f2P[ii] = f2bf(f2w[i_t * 8192 + (ct * 16 + l15) * 128 + p * 64 + ks * 32 + quad * 8 + j]);
    }
    return;
  }
  if (bid == 384) {   // style
    int b = tid >> 6;
    int c = tid & 63;
    float a = 0.f;
    const float* ip = istyle + b * 512;
    const float* wp = sw + c * 512;
    for (int l = 0; l < 512; ++l) a += ip[l] * wp[l];
    styleb[b * 64 + c] = a + sb[c];
    return;
  }
  if (bid < 513) {   // wnorm: demod weight prep -> frag-packed
    int wb_ = bid - 385;
    int which = wb_ >> 6;
    int co = wb_ & 63;
    const float* W = which ? W2 : W1;
    short* wbP = which ? wb2 : wb1;
    int CI = which ? 64 : 128;
    int n = CI * 9;
    int KS = CI >> 5;
    float* red = shmem;
    float s = 0.f;
    for (int idx = tid; idx < n; idx += 256) {
      float w2 = 2.0f * W[co * n + idx];
      s += w2 * w2;
    }
    red[tid] = s;
    __syncthreads();
    for (int off = 128; off > 0; off >>= 1) {
      if (tid < off) red[tid] += red[tid + off];
      __syncthreads();
    }
    float sc = rsqrtf(red[0] + 1e-8f);
    int ct = co >> 4, l15 = co & 15;
    for (int idx = tid; idx < n; idx += 256) {
      int ci = idx / 9, k = idx - ci * 9;
      int ks = ci >> 5, quad = (ci >> 3) & 3, j = ci & 7;
      wbP[((k * 4 + ct) * KS + ks) * 512 + (quad * 16 + l15) * 8 + j] =
          f2bf(2.0f * W[co * n + idx] * sc);
    }
    return;
  }
  // up2t: fused bilinear up2 + NCHW->NHWC bf16, coalesced stores
  int idx0 = bid - 513;
  int b = idx0 >> 7, y = idx0 & 127;
  int w = tid >> 6, lane = tid & 63, quad = lane >> 4, l15 = lane & 15;
  float* row = shmem;   // [xin64][c pad132]
  float iy = y * 0.5f - 0.25f;
  int y0 = (int)floorf(iy); float wy = iy - (float)y0;
  int ylo = y0 < 0 ? 0 : y0;
  int yhi = y0 + 1 > 63 ? 63 : y0 + 1;
  for (int it = 0; it < 32; ++it) {
    int idx = it * 256 + tid;
    int c = idx >> 6, xi = idx & 63;
    const float* bp = xin + ((long)(b * 128 + c)) * 4096;
    float v0 = bp[ylo * 64 + xi];
    float v1 = bp[yhi * 64 + xi];
    row[xi * 132 + c] = (1.f - wy) * v0 + wy * v1;
  }
  __syncthreads();
  long ybase = (((long)(b * 128 + y)) * 128) * 128;
#pragma unroll
  for (int s = 0; s < 8; ++s) {
    int x = w * 32 + s * 4 + quad;
    float ix = x * 0.5f - 0.25f;
    int x0 = (int)floorf(ix); float wx = ix - (float)x0;
    int xlo = x0 < 0 ? 0 : x0;
    int xhi = x0 + 1 > 63 ? 63 : x0 + 1;
    bf16x8 pack;
#pragma unroll
    for (int j = 0; j < 8; ++j) {
      int c = l15 * 8 + j;
      float v = (1.f - wx) * row[xlo * 132 + c] + wx * row[xhi * 132 + c];
      pack[j] = f2bf(v);
    }
    *(bf16x8*)(xupT + ybase + (long)x * 128 + l15 * 8) = pack;
  }
}

// ---------------- pk: Gpart = exp(kw@X) @ [X^T | 1 | 0]; packs nzP; kw loads pipelined ---
__global__ __launch_bounds__(256, 4) void pk_kernel(const float* __restrict__ nz1,
                                                    const float* __restrict__ nz2,
                                                    short* __restrict__ nzP,
                                                    const short* __restrict__ kwP,
                                                    short* __restrict__ Gpartb) {
  __shared__ __attribute__((aligned(16))) char lds[39168];
  int bi = blockIdx.x, ch = blockIdx.y;
  int i = bi >> 2, b = bi & 3;
  const float* nz = (i == 0) ? nz1 : nz2;
  const short* kwP_i = kwP + i * (DK * NF);
  int tid = threadIdx.x;
  int w = tid >> 6, lane = tid & 63, quad = lane >> 4, l15 = lane & 15;
  int n0 = ch * 128;
  short* Xb = (short*)lds;               // [80][136]
  short* Ph = (short*)(lds + 21760);     // [64][136]
  // float4 staging: wave = 2 c-rows x 512B contiguous
#pragma unroll
  for (int k = 0; k < 8; ++k) {
    int idx = tid + k * 256;
    int c = idx >> 5, g = idx & 31;
    float4 v = *(const float4*)(nz + ((long)b * 64 + c) * NPIX + n0 + g * 4);
    short* xp = Xb + c * 136 + g * 4;
    xp[0] = f2bf(v.x); xp[1] = f2bf(v.y); xp[2] = f2bf(v.z); xp[3] = f2bf(v.w);
  }
  for (int k = 0; k < 8; ++k) {
    int idx = tid + k * 256;
    int c = 64 + (idx >> 7), n = idx & 127;
    Xb[c * 136 + n] = (c == 64) ? (short)0x3F80 : (short)0;
  }
  // preload q=0's kw fragments while staging drains
  bf16x8 kf[2][4];
#pragma unroll
  for (int ks = 0; ks < 2; ++ks)
#pragma unroll
    for (int dt = 0; dt < 4; ++dt)
      kf[ks][dt] = *(const bf16x8*)(kwP_i + ((dt * 2 + ks) * 512 + lane * 8));
  __syncthreads();
  // pack the 16 nzP fragments (8 ntiles x 2 ks) for this 128-px chunk: 1024 slots
  long fragb = (long)bi * 1024 + ch * 8;
#pragma unroll
  for (int v = 0; v < 4; ++v) {
    int slot = tid + v * 256;
    int frag = slot >> 6, ln = slot & 63;
    int nt = frag >> 1, ksf = frag & 1;
    int fl15 = ln & 15, fq = ln >> 4;
    bf16x8 pack;
#pragma unroll
    for (int j = 0; j < 8; ++j)
      pack[j] = Xb[(ksf * 32 + fq * 8 + j) * 136 + nt * 16 + fl15];
    *(bf16x8*)(nzP + ((fragb + nt) * 2 + ksf) * 512 + ln * 8) = pack;
  }
  // build this wave's B fragments from Xb
  bf16x8 bfr[2][2];
#pragma unroll
  for (int j = 0; j < 2; ++j)
#pragma unroll
    for (int ks = 0; ks < 2; ++ks)
#pragma unroll
      for (int jj = 0; jj < 8; ++jj)
        bfr[j][ks][jj] = Xb[(ks * 32 + quad * 8 + jj) * 136 + (2 * w + j) * 16 + l15];
  for (int q = 0; q < 4; ++q) {
    f32x4 acc[2][4];
#pragma unroll
    for (int j = 0; j < 2; ++j)
#pragma unroll
      for (int dt = 0; dt < 4; ++dt) acc[j][dt] = (f32x4){0.f, 0.f, 0.f, 0.f};
#pragma unroll
    for (int j = 0; j < 2; ++j)
#pragma unroll
      for (int ks = 0; ks < 2; ++ks)
#pragma unroll
        for (int dt = 0; dt < 4; ++dt)
          acc[j][dt] = MFMA16(kf[ks][dt], bfr[j][ks], acc[j][dt]);
    // prefetch next q's kw fragments -- latency hides under exp + Ph + barrier + G-GEMM
    if (q < 3) {
#pragma unroll
      for (int ks = 0; ks < 2; ++ks)
#pragma unroll
        for (int dt = 0; dt < 4; ++dt)
          kf[ks][dt] = *(const bf16x8*)(kwP_i +
              ((((q + 1) * 4 + dt) * 2 + ks) * 512 + lane * 8));
    }
#pragma unroll
    for (int j = 0; j < 2; ++j) {
      int ntile = 2 * w + j;
#pragma unroll
      for (int dt = 0; dt < 4; ++dt)
#pragma unroll
        for (int r = 0; r < 4; ++r) {
          float p = __expf(acc[j][dt][r] * QKSCALE);
          Ph[(dt * 16 + quad * 4 + r) * 136 + ntile * 16 + l15] = f2bf(p);
        }
    }
    __syncthreads();
#pragma unroll
    for (int ct = 0; ct < 5; ++ct) {
      f32x4 g = (f32x4){0.f, 0.f, 0.f, 0.f};
#pragma unroll
      for (int ks = 0; ks < 4; ++ks) {
        bf16x8 afr = *(const bf16x8*)(Ph + (w * 16 + l15) * 136 + ks * 32 + quad * 8);
        bf16x8 bfr2 = *(const bf16x8*)(Xb + (ct * 16 + l15) * 136 + ks * 32 + quad * 8);
        g = MFMA16(afr, bfr2, g);
      }
#pragma unroll
      for (int r = 0; r < 4; ++r) {
        int row = q * 64 + w * 16 + quad * 4 + r;
        Gpartb[(((long)bi * 128 + ch) * 256 + row) * 80 + ct * 16 + l15] = f2bf(g[r]);
      }
    }
    __syncthreads();
  }
}

// ---------------- gsum: reduce Gpart over ch -> Gsum fp32 [bi][256][80], short4/lane -----
__global__ __launch_bounds__(256) void gsum_kernel(const short* __restrict__ Gpartb,
                                                   float* __restrict__ Gsum) {
  int idx4 = blockIdx.x * 256 + threadIdx.x;   // 40960 total
  int bi = idx4 / 5120;
  int rem4 = idx4 - bi * 5120;
  const short* gp = Gpartb + (long)bi * 128 * 20480 + rem4 * 4;
  float a0 = 0.f, a1 = 0.f, a2 = 0.f, a3 = 0.f;
#pragma unroll 8
  for (int ch = 0; ch < 128; ++ch) {
    short4 v = *(const short4*)(gp + (long)ch * 20480);
    a0 += bf2f(v.x); a1 += bf2f(v.y); a2 += bf2f(v.z); a3 += bf2f(v.w);
  }
  float4 o = {a0, a1, a2, a3};
  *(float4*)(Gsum + (long)bi * 20480 + rem4 * 4) = o;
}

// ---------------- ctxM: Gsum -> ctx -> MtP (fragment-packed) -----------------------------
__global__ __launch_bounds__(256) void ctxM_kernel(const float* __restrict__ Gsum,
                                                   const float* __restrict__ vw,
                                                   const float* __restrict__ ow,
                                                   short* __restrict__ MtP) {
  int i = blockIdx.z, b = blockIdx.y, dt = blockIdx.x * 16;
  int h = dt >> 5;
  __shared__ float Gs[16][81];
  __shared__ float ctxs[16][68];
  int t = threadIdx.x;
  const float* gsb = Gsum + ((long)(i * NB + b)) * 20480;
  for (int idx = t; idx < 1280; idx += 256) {
    int dl = idx / 80, c = idx - dl * 80;
    Gs[dl][c] = gsb[(dt + dl) * 80 + c];
  }
  __syncthreads();
  const float* vw_i = vw + (long)i * DV * NF;
  const float* ow_i = ow + (long)i * NF * DV;
  for (int idx = t; idx < 1024; idx += 256) {
    int dl = idx & 15, e = idx >> 4;
    const float* vp = vw_i + (h * 64 + e) * 64;
    float a = 0.f;
#pragma unroll
    for (int c = 0; c < 64; ++c) a += Gs[dl][c] * vp[c];
    ctxs[dl][e] = a / Gs[dl][64];
  }
  __syncthreads();
  // MtP[bi][ct4][h8][lane][8] = MtT[c=ct*16+l15][d=h*32+quad*8+r]
  short* mtp = MtP + ((long)(i * NB + b)) * 16384;
  for (int idx = t; idx < 1024; idx += 256) {
    int dl = idx & 15, c = idx >> 4;
    const float* op = ow_i + c * 512 + h * 64;
    float a = 0.f;
#pragma unroll
    for (int e = 0; e < 64; ++e) a += op[e] * ctxs[dl][e];
    int d = dt + dl;
    int ct = c >> 4, l15 = c & 15, hh = d >> 5, quad = (d >> 3) & 3, r = d & 7;
    mtp[((ct * 8 + hh) * 64 + quad * 16 + l15) * 8 + r] = f2bf(a);
  }
}

// ---------------- attnd4: fused attn+FF, software-pipelined A-fragment loads -------------
// grid (8 bi, 256 x), block 256 = 4 waves, 16 px/wave. Per-wave LDS 4096 B.
__global__ __launch_bounds__(256, 5) void attnd4_kernel(
    const short* __restrict__ nzP, const short* __restrict__ qwP,
    const short* __restrict__ MtP, const float* __restrict__ ob,
    const float* __restrict__ gap, const short* __restrict__ f1P,
    const float* __restrict__ f1b, const short* __restrict__ f2P,
    const float* __restrict__ f2b, const float* __restrict__ gfp,
    short* __restrict__ noutP) {
  __shared__ __attribute__((aligned(16))) short lds[4 * 2048];
  int bi = blockIdx.x;
  int i = bi >> 2;
  int tid = threadIdx.x;
  int w = tid >> 6, lane = tid & 63, quad = lane >> 4, l15 = lane & 15;
  short* Xt = lds + w * 2048;     // [16][72]
  short* Es = Xt + 1152;          // [16][56]
  float ga = gap[i], gf = gfp[i];
  const short* qwP_i = qwP + i * (DK * NF);
  const short* f1P_i = f1P + i * (128 * 64);
  const float* f1b_i = f1b + i * 128;
  const short* f2P_i = f2P + i * (64 * 128);
  const float* f2b_i = f2b + i * 64;
  const float* ob_i = ob + i * 64;
  long ntile = (long)bi * 1024 + blockIdx.y * 4 + w;
  // stage X: two fully-coalesced 1KB fragment loads, mirror into LDS for residual
  const short* nb = nzP + ntile * 1024;
  bf16x8 xfr0 = *(const bf16x8*)(nb + lane * 8);
  bf16x8 xfr1 = *(const bf16x8*)(nb + 512 + lane * 8);
  *(bf16x8*)(Xt + l15 * 72 + quad * 8) = xfr0;
  *(bf16x8*)(Xt + l15 * 72 + 32 + quad * 8) = xfr1;
  const short* mtp = MtP + (long)bi * 16384;
  f32x4 acc2[4];
#pragma unroll
  for (int ct = 0; ct < 4; ++ct) acc2[ct] = (f32x4){0.f, 0.f, 0.f, 0.f};
  // preload head 0's qw fragments
  bf16x8 qa00 = *(const bf16x8*)(qwP_i + 0 * 512 + lane * 8);
  bf16x8 qa01 = *(const bf16x8*)(qwP_i + 1 * 512 + lane * 8);
  bf16x8 qa10 = *(const bf16x8*)(qwP_i + 2 * 512 + lane * 8);
  bf16x8 qa11 = *(const bf16x8*)(qwP_i + 3 * 512 + lane * 8);
  // per-head: GEMM1 (q) -> softmax -> E-strip -> GEMM2 chunk; A-loads pipelined
#pragma unroll
  for (int h = 0; h < 8; ++h) {
    // issue this head's mtp fragment loads NOW (latency hides under softmax)
    bf16x8 m0 = *(const bf16x8*)(mtp + (0 * 8 + h) * 512 + lane * 8);
    bf16x8 m1 = *(const bf16x8*)(mtp + (1 * 8 + h) * 512 + lane * 8);
    bf16x8 m2 = *(const bf16x8*)(mtp + (2 * 8 + h) * 512 + lane * 8);
    bf16x8 m3 = *(const bf16x8*)(mtp + (3 * 8 + h) * 512 + lane * 8);
    f32x4 q[2];
    q[0] = (f32x4){0.f, 0.f, 0.f, 0.f};
    q[0] = MFMA16(qa00, xfr0, q[0]);
    q[0] = MFMA16(qa01, xfr1, q[0]);
    q[1] = (f32x4){0.f, 0.f, 0.f, 0.f};
    q[1] = MFMA16(qa10, xfr0, q[1]);
    q[1] = MFMA16(qa11, xfr1, q[1]);
    // prefetch next head's qw fragments (in flight during softmax + GEMM2)
    if (h < 7) {
      int hn = 2 * (h + 1);
      qa00 = *(const bf16x8*)(qwP_i + (hn * 2 + 0) * 512 + lane * 8);
      qa01 = *(const bf16x8*)(qwP_i + (hn * 2 + 1) * 512 + lane * 8);
      qa10 = *(const bf16x8*)(qwP_i + ((hn + 1) * 2 + 0) * 512 + lane * 8);
      qa11 = *(const bf16x8*)(qwP_i + ((hn + 1) * 2 + 1) * 512 + lane * 8);
    }
    float part = 0.f;
#pragma unroll
    for (int dd = 0; dd < 2; ++dd)
#pragma unroll
      for (int r = 0; r < 4; ++r) {
        float e = __expf(q[dd][r] * QKSCALE);
        q[dd][r] = e;
        part += e;
      }
    float p2 = part + __shfl_xor(part, 16);
    float s = p2 + __shfl_xor(p2, 32);
    float inv = 1.0f / s;
#pragma unroll
    for (int dd = 0; dd < 2; ++dd) {
      short4 ev;
      ev.x = f2bf(q[dd][0] * inv); ev.y = f2bf(q[dd][1] * inv);
      ev.z = f2bf(q[dd][2] * inv); ev.w = f2bf(q[dd][3] * inv);
      *(short4*)(Es + l15 * 56 + dd * 16 + quad * 4) = ev;
    }
    bf16x8 efr = *(const bf16x8*)(Es + l15 * 56 + quad * 8);
    acc2[0] = MFMA16(m0, efr, acc2[0]);
    acc2[1] = MFMA16(m1, efr, acc2[1]);
    acc2[2] = MFMA16(m2, efr, acc2[2]);
    acc2[3] = MFMA16(m3, efr, acc2[3]);
  }
  // residual y = x + ga*(o + ob): x from LDS bf16, y back to Xt + fp32 regs
  float yreg[4][4];
#pragma unroll
  for (int ct = 0; ct < 4; ++ct) {
    int c0 = ct * 16 + quad * 4;
    short4 xs = *(const short4*)(Xt + l15 * 72 + c0);
    float xv[4] = {bf2f(xs.x), bf2f(xs.y), bf2f(xs.z), bf2f(xs.w)};
    short4 ys;
#pragma unroll
    for (int r = 0; r < 4; ++r) yreg[ct][r] = xv[r] + ga * (acc2[ct][r] + ob_i[c0 + r]);
    ys.x = f2bf(yreg[ct][0]); ys.y = f2bf(yreg[ct][1]);
    ys.z = f2bf(yreg[ct][2]); ys.w = f2bf(yreg[ct][3]);
    *(short4*)(Xt + l15 * 72 + c0) = ys;
  }
  bf16x8 yfr0 = *(const bf16x8*)(Xt + l15 * 72 + quad * 8);
  bf16x8 yfr1 = *(const bf16x8*)(Xt + l15 * 72 + 32 + quad * 8);
  // GEMM3: h1[128j x 16n]
  f32x4 acc3[8];
#pragma unroll
  for (int jt = 0; jt < 8; ++jt) {
    acc3[jt] = (f32x4){0.f, 0.f, 0.f, 0.f};
    bf16x8 a0 = *(const bf16x8*)(f1P_i + (jt * 2 + 0) * 512 + lane * 8);
    acc3[jt] = MFMA16(a0, yfr0, acc3[jt]);
    bf16x8 a1 = *(const bf16x8*)(f1P_i + (jt * 2 + 1) * 512 + lane * 8);
    acc3[jt] = MFMA16(a1, yfr1, acc3[jt]);
  }
  // GEMM4 in 2 chunks of 64 j through the Xt strip
  f32x4 acc4[4];
#pragma unroll
  for (int ct = 0; ct < 4; ++ct) acc4[ct] = (f32x4){0.f, 0.f, 0.f, 0.f};
#pragma unroll
  for (int p = 0; p < 2; ++p) {
#pragma unroll
    for (int jj = 0; jj < 4; ++jj) {
      int jt = p * 4 + jj;
      short4 hs;
#pragma unroll
      for (int r = 0; r < 4; ++r) {
        float a = acc3[jt][r] + f1b_i[jt * 16 + quad * 4 + r];
        a = a > 0.f ? a : 0.2f * a;
        ((short*)&hs)[r] = f2bf(a);
      }
      *(short4*)(Xt + l15 * 72 + jj * 16 + quad * 4) = hs;
    }
    bf16x8 h0 = *(const bf16x8*)(Xt + l15 * 72 + quad * 8);
    bf16x8 h1 = *(const bf16x8*)(Xt + l15 * 72 + 32 + quad * 8);
#pragma unroll
    for (int ct = 0; ct < 4; ++ct) {
      bf16x8 a0 = *(const bf16x8*)(f2P_i + ((ct * 2 + p) * 2 + 0) * 512 + lane * 8);
      acc4[ct] = MFMA16(a0, h0, acc4[ct]);
      bf16x8 a1 = *(const bf16x8*)(f2P_i + ((ct * 2 + p) * 2 + 1) * 512 + lane * 8);
      acc4[ct] = MFMA16(a1, h1, acc4[ct]);
    }
  }
  // output fragment-packed: noutP[ntile][ct][lane][4] -- 512B coalesced per store
#pragma unroll
  for (int ct = 0; ct < 4; ++ct) {
    int c0 = ct * 16 + quad * 4;
    short4 ov;
#pragma unroll
    for (int r = 0; r < 4; ++r)
      ((short*)&ov)[r] = f2bf(yreg[ct][r] + gf * (acc4[ct][r] + f2b_i[c0 + r]));
    *(short4*)(noutP + (ntile * 4 + ct) * 256 + lane * 4) = ov;
  }
}

// ---------------- MFMA 3x3 conv: weight loads software-pipelined (R12 recipe) ------------
// grid (2 xh, 128 y, NB). wave w -> one 16-px ntile; block covers 64 px (half row).
__global__ __launch_bounds__(256, 4) void convmfma_kernel(
    const short* __restrict__ inT, int CI, const short* __restrict__ wbP,
    const short* __restrict__ addnP, float* __restrict__ out_nchw,
    short* __restrict__ out_nhwc, const float* __restrict__ rgbw,
    const float* __restrict__ styleb, const float* __restrict__ prev,
    float* __restrict__ rgbs) {
  __shared__ __attribute__((aligned(16))) short Bs[3 * 66 * 40];  // [r][xi][ci32 pad40]
  int xh = blockIdx.x, y = blockIdx.y, b = blockIdx.z;
  int tid = threadIdx.x;
  int w = tid >> 6, lane = tid & 63, quad = lane >> 4, l15 = lane & 15;
  int KS = CI >> 5;
  const short* wlane = wbP + lane * 8;
  f32x4 acc[4];
#pragma unroll
  for (int ct = 0; ct < 4; ++ct) acc[ct] = (f32x4){0.f, 0.f, 0.f, 0.f};
  // preload (ks=0, sh=0)'s 4 weight fragments
  bf16x8 wa0 = *(const bf16x8*)(wlane);
  bf16x8 wa1 = *(const bf16x8*)(wlane + KS * 512);
  bf16x8 wa2 = *(const bf16x8*)(wlane + 2 * KS * 512);
  bf16x8 wa3 = *(const bf16x8*)(wlane + 3 * KS * 512);
  for (int ks = 0; ks < KS; ++ks) {
    if (ks) __syncthreads();
    for (int t = tid; t < 792; t += 256) {
      int ci8 = t & 3, xr = t >> 2;
      int xi = xr % 66, r = xr / 66;
      int gy = y + r - 1, gx = xh * 64 + xi - 1;
      bf16x8 v = {0, 0, 0, 0, 0, 0, 0, 0};
      if (gy >= 0 && gy < 128 && gx >= 0 && gx < 128)
        v = *(const bf16x8*)(inT + (((long)(b * 128 + gy)) * 128 + gx) * CI + ks * 32 + ci8 * 8);
      *(bf16x8*)(Bs + (r * 66 + xi) * 40 + ci8 * 8) = v;
    }
    __syncthreads();
#pragma unroll
    for (int sh = 0; sh < 9; ++sh) {
      int dyv = sh / 3, dxv = sh - dyv * 3;
      // consume current weights; issue next (sh+1 | ks+1,sh=0) loads under the MFMAs
      bf16x8 c0 = wa0, c1 = wa1, c2 = wa2, c3 = wa3;
      if (sh < 8) {
        const short* nb = wlane + (((sh + 1) * 4) * KS + ks) * 512;
        wa0 = *(const bf16x8*)(nb);
        wa1 = *(const bf16x8*)(nb + KS * 512);
        wa2 = *(const bf16x8*)(nb + 2 * KS * 512);
        wa3 = *(const bf16x8*)(nb + 3 * KS * 512);
      } else if (ks + 1 < KS) {
        const short* nb = wlane + (long)(ks + 1) * 512;
        wa0 = *(const bf16x8*)(nb);
        wa1 = *(const bf16x8*)(nb + KS * 512);
        wa2 = *(const bf16x8*)(nb + 2 * KS * 512);
        wa3 = *(const bf16x8*)(nb + 3 * KS * 512);
      }
      int xi = w * 16 + l15 + dxv;
      bf16x8 bf = *(const bf16x8*)(Bs + (dyv * 66 + xi) * 40 + quad * 8);
      acc[0] = MFMA16(c0, bf, acc[0]);
      acc[1] = MFMA16(c1, bf, acc[1]);
      acc[2] = MFMA16(c2, bf, acc[2]);
      acc[3] = MFMA16(c3, bf, acc[3]);
    }
  }
  // epilogue: lrelu(conv + addn(frag-packed)), stores, optional rgb
  int x = xh * 64 + w * 16 + l15;
  long nidx = ((long)(b * 128 + y)) * 128 + x;
  long ntile = (long)b * 1024 + y * 8 + xh * 4 + w;
  float p0 = 0.f, p1 = 0.f, p2 = 0.f;
#pragma unroll
  for (int ct = 0; ct < 4; ++ct) {
    short4 ad = *(const short4*)(addnP + (ntile * 4 + ct) * 256 + lane * 4);
    float av[4] = {bf2f(ad.x), bf2f(ad.y), bf2f(ad.z), bf2f(ad.w)};
    float v[4];
#pragma unroll
    for (int r = 0; r < 4; ++r) {
      float a = acc[ct][r] + av[r];
      v[r] = a > 0.f ? a : 0.2f * a;
    }
    if (out_nchw) {
#pragma unroll
      for (int r = 0; r < 4; ++r) {
        int co = ct * 16 + quad * 4 + r;
        out_nchw[((long)(b * 64 + co)) * 16384 + y * 128 + x] = v[r];
      }
    }
    if (out_nhwc) {
      short4 pv;
      pv.x = f2bf(v[0]); pv.y = f2bf(v[1]); pv.z = f2bf(v[2]); pv.w = f2bf(v[3]);
      *(short4*)(out_nhwc + nidx * 64 + ct * 16 + quad * 4) = pv;
    }
    if (rgbw) {
#pragma unroll
      for (int r = 0; r < 4; ++r) {
        int co = ct * 16 + quad * 4 + r;
        float mv = (styleb[b * 64 + co] + 1.0f) * v[r];
        p0 += rgbw[co] * mv;
        p1 += rgbw[64 + co] * mv;
        p2 += rgbw[128 + co] * mv;
      }
    }
  }
  if (rgbw) {
    p0 += __shfl_xor(p0, 16); p0 += __shfl_xor(p0, 32);
    p1 += __shfl_xor(p1, 16); p1 += __shfl_xor(p1, 32);
    p2 += __shfl_xor(p2, 16); p2 += __shfl_xor(p2, 32);
    if (quad == 0) {
      long pi = y * 128 + x;
      rgbs[((long)(b * 3 + 0)) * 16384 + pi] = p0 + prev[((long)(b * 3 + 0)) * 16384 + pi];
      rgbs[((long)(b * 3 + 1)) * 16384 + pi] = p1 + prev[((long)(b * 3 + 1)) * 16384 + pi];
      rgbs[((long)(b * 3 + 2)) * 16384 + pi] = p2 + prev[((long)(b * 3 + 2)) * 16384 + pi];
    }
  }
}

// ---------------- fused bilinear up2 + [1,2,1] blur (rgb tail) ---------------------------
__global__ void upblur_kernel(const float* __restrict__ rgbs, float* __restrict__ out) {
  __shared__ float rows[3][128];
  int bc = blockIdx.y, Y = blockIdx.x, X = threadIdx.x;
  int m = Y >> 1;
  const float* base = rgbs + (long)bc * 16384;
  for (int t = X; t < 384; t += 256) {
    int sr = t >> 7, xx = t & 127;
    int rr = m - 1 + sr;
    rr = rr < 0 ? 0 : (rr > 127 ? 127 : rr);
    rows[sr][xx] = base[rr * 128 + xx];
  }
  __syncthreads();
  const float w3[3] = {1.f, 2.f, 1.f};
  float s = 0.f;
#pragma unroll
  for (int dy = -1; dy <= 1; ++dy) {
    int Yv = Y + dy;
    if (Yv < 0 || Yv > 255) continue;
    float iy = Yv * 0.5f - 0.25f;
    int y0 = (int)floorf(iy); float wy = iy - (float)y0;
    int ylo = y0 < 0 ? 0 : y0;
    int yhi = y0 + 1 > 127 ? 127 : y0 + 1;
    int slo = ylo - m + 1, shi = yhi - m + 1;
#pragma unroll
    for (int dx = -1; dx <= 1; ++dx) {
      int Xv = X + dx;
      if (Xv < 0 || Xv > 255) continue;
      float ix = Xv * 0.5f - 0.25f;
      int x0 = (int)floorf(ix); float wx = ix - (float)x0;
      int xlo = x0 < 0 ? 0 : x0;
      int xhi = x0 + 1 > 127 ? 127 : x0 + 1;
      float v = (1.f - wy) * ((1.f - wx) * rows[slo][xlo] + wx * rows[slo][xhi])
              + wy * ((1.f - wx) * rows[shi][xlo] + wx * rows[shi][xhi]);
      s += w3[dy + 1] * w3[dx + 1] * v;
    }
  }
  out[(long)bc * 65536 + Y * 256 + X] = s * (1.0f / 16.0f);
}

extern "C" void kernel_launch(void* const* d_in, const int* in_sizes, int n_in,
                              void* d_out, int out_size, void* d_ws, size_t ws_size,
                              hipStream_t stream) {
  (void)in_sizes; (void)n_in; (void)out_size; (void)ws_size;
  const float* x        = (const float*)d_in[0];
  const float* prev_rgb = (const float*)d_in[1];
  const float* istyle   = (const float*)d_in[2];
  const float* noise1   = (const float*)d_in[3];
  const float* noise2   = (const float*)d_in[4];
  const float* conv1_w  = (const float*)d_in[5];
  const float* conv2_w  = (const float*)d_in[6];
  const float* style_w  = (const float*)d_in[7];
  const float* style_b  = (const float*)d_in[8];
  const float* rgb_w    = (const float*)d_in[9];
  const float* qw       = (const float*)d_in[10];
  const float* kw       = (const float*)d_in[11];
  const float* vw       = (const float*)d_in[12];
  const float* ow       = (const float*)d_in[13];
  const float* ob       = (const float*)d_in[14];
  const float* ga       = (const float*)d_in[15];
  const float* f1w      = (const float*)d_in[16];
  const float* f1b      = (const float*)d_in[17];
  const float* f2w      = (const float*)d_in[18];
  const float* f2b      = (const float*)d_in[19];
  const float* gf       = (const float*)d_in[20];
  float* out_x   = (float*)d_out;
  float* out_rgb = out_x + 4194304;
  float* ws = (float*)d_ws;

  short* xupT   = (short*)(ws + OFF_XUPT);
  short* xaT    = (short*)(ws + OFF_XAT);
  short* nbufP  = (short*)(ws + OFF_NBT);
  short* nzP    = (short*)(ws + OFF_NZT);
  short* Gpartb = (short*)(ws + OFF_GPART);
  short* wb1    = (short*)(ws + OFF_WB1);
  short* wb2    = (short*)(ws + OFF_WB2);
  float* styleb = ws + OFF_STYLE;
  float* rgbs   = ws + OFF_RGBS;
  short* qwP    = (short*)(ws + OFF_QWB);
  short* kwP    = (short*)(ws + OFF_KWB);
  short* f1P    = (short*)(ws + OFF_F1WB);
  short* f2P    = (short*)(ws + OFF_F2WB);
  short* MtP    = (short*)(ws + OFF_MTT);
  float* Gsum   = ws + OFF_GSUM;

  // fused prep: cvt4+style | wnorm2 | up2t (all independent, one launch)
  prep_kernel<<<1025, 256, 0, stream>>>(qw, kw, f1w, f2w, qwP, kwP, f1P, f2P,
                                        istyle, style_w, style_b, styleb,
                                        conv1_w, conv2_w, wb1, wb2, x, xupT);

  // attention path (pk also packs nzP)
  pk_kernel<<<dim3(8, 128), 256, 0, stream>>>(noise1, noise2, nzP, kwP, Gpartb);
  gsum_kernel<<<160, 256, 0, stream>>>(Gpartb, Gsum);
  ctxM_kernel<<<dim3(16, NB, 2), 256, 0, stream>>>(Gsum, vw, ow, MtP);
  attnd4_kernel<<<dim3(8, 256), 256, 0, stream>>>(nzP, qwP, MtP, ob, ga,
                                                  f1P, f1b, f2P, f2b, gf, nbufP);

  // conv chain (dependent, stays serial)
  convmfma_kernel<<<dim3(2, 128, NB), 256, 0, stream>>>(
      xupT, 128, wb1, nbufP, nullptr, xaT, nullptr, nullptr, nullptr, nullptr);
  convmfma_kernel<<<dim3(2, 128, NB), 256, 0, stream>>>(
      xaT, 64, wb2, nbufP + 4194304L, out_x, nullptr, rgb_w, styleb, prev_rgb, rgbs);

  upblur_kernel<<<dim3(256, 12), 256, 0, stream>>>(rgbs, out_rgb);
}